// Round 4
// baseline (849.029 us; speedup 1.0000x reference)
//
#include <hip/hip_runtime.h>
#include <hip/hip_bf16.h>
#include <hip/hip_fp16.h>

#define NN   102400
#define NG   64
#define NPG  1600
#define EPG  25600

// wLDS layout (floats)
#define W_ENI  0     // enc Wni [16][8]
#define W_HES  128   // hid Wes [8][16]
#define W_HNN  256   // hid Wnn [16][16]
#define W_HNI  512   // hid Wni [16][8]
#define W_HEE  640   // hid Wee [8][8]
// red layout (floats)
#define R_ES1  0     // 8
#define R_NS1  8     // 16
#define R_ES2  24    // 8
#define R_NS2  32    // 16
#define R_G1   48    // 4
#define R_GPE  52    // 8  (incl hbe)
#define R_GPN  60    // 16 (incl hbn)
#define R_G2   80    // 4

__device__ __forceinline__ void store_h8(__half* p, const float* v) {
    __half2* q = (__half2*)p;
#pragma unroll
    for (int i = 0; i < 4; ++i) q[i] = __floats2half2_rn(v[2 * i], v[2 * i + 1]);
}
__device__ __forceinline__ void load_h8(const __half* p, float* v) {
    const __half2* q = (const __half2*)p;
#pragma unroll
    for (int i = 0; i < 4; ++i) { float2 a = __half22float2(q[i]); v[2 * i] = a.x; v[2 * i + 1] = a.y; }
}
__device__ __forceinline__ void store_h16(__half* p, const float* v) {
    __half2* q = (__half2*)p;
#pragma unroll
    for (int i = 0; i < 8; ++i) q[i] = __floats2half2_rn(v[2 * i], v[2 * i + 1]);
}
__device__ __forceinline__ void load_h16(const __half* p, float* v) {
    const __half2* q = (const __half2*)p;
#pragma unroll
    for (int i = 0; i < 8; ++i) { float2 a = __half22float2(q[i]); v[2 * i] = a.x; v[2 * i + 1] = a.y; }
}

__global__ __launch_bounds__(512) void gn_fused(
    const float* __restrict__ nf, const float* __restrict__ ef,
    const int* __restrict__ snd, const int* __restrict__ rcv,
    const float* __restrict__ eWee, const float* __restrict__ eWes, const float* __restrict__ ebe,
    const float* __restrict__ eWnn, const float* __restrict__ eWni, const float* __restrict__ ebn,
    const float* __restrict__ eWge, const float* __restrict__ eWgn, const float* __restrict__ ebg,
    const float* __restrict__ hWee, const float* __restrict__ hWes, const float* __restrict__ hWeg,
    const float* __restrict__ hbe,  const float* __restrict__ hWnn, const float* __restrict__ hWni,
    const float* __restrict__ hWng, const float* __restrict__ hbn,
    const float* __restrict__ hWge, const float* __restrict__ hWgn, const float* __restrict__ hWgg,
    const float* __restrict__ hbg,  const float* __restrict__ roWn, const float* __restrict__ robn,
    const float* __restrict__ roWg, const float* __restrict__ robg,
    float* __restrict__ outn, float* __restrict__ outg)
{
    // 60,800 B of f32 LDS + 102,400 B of f16 LDS = 163,200 B (<= 160 KiB)
    __shared__ float  smemF[15200];   // [0,14400) accL [1600][9]; [14400,15104) wLDS; [15104,15200) red
    __shared__ __half smemH[51200];   // [0,12800) sprojH [1600][8]; [12800,25600) pes2H [1600][8]; [25600,51200) n1H [1600][16]
    float*  accL   = smemF;
    float*  wLDS   = smemF + 14400;
    float*  red    = smemF + 15104;
    __half* sprojH = smemH;
    __half* pes2H  = smemH + 12800;
    __half* n1H    = smemH + 25600;

    const int g   = blockIdx.x;
    const int tid = threadIdx.x;

    // ---- P0: stage small weights; big enc weights (eWes,eWnn) temporarily in accL; zero red ----
    for (int i = tid; i < 128; i += 512) { wLDS[W_ENI + i] = eWni[i]; wLDS[W_HES + i] = hWes[i]; wLDS[W_HNI + i] = hWni[i]; }
    for (int i = tid; i < 256; i += 512) wLDS[W_HNN + i] = hWnn[i];
    for (int i = tid; i < 64;  i += 512) wLDS[W_HEE + i] = hWee[i];
    for (int i = tid; i < 480; i += 512) accL[i]       = eWes[i];   // [0,480): Wes [8][60]
    for (int i = tid; i < 960; i += 512) accL[480 + i] = eWnn[i];   // [480,1440): Wnn [16][60]
    if (tid < 96) red[tid] = 0.f;
    __syncthreads();

    // ---- P1: per-node encoder pre-projections (pes -> sprojH, pnn -> n1H region) ----
    for (int v = tid; v < NPG; v += 512) {
        const float4* row = reinterpret_cast<const float4*>(nf + (size_t)(g * NPG + v) * 60);
        float x[60];
#pragma unroll
        for (int i = 0; i < 15; ++i) {
            const float4 a = row[i];
            x[4 * i] = a.x; x[4 * i + 1] = a.y; x[4 * i + 2] = a.z; x[4 * i + 3] = a.w;
        }
        float pes[8], pn[16];
#pragma unroll
        for (int j = 0; j < 8; ++j) pes[j] = 0.f;
#pragma unroll
        for (int j = 0; j < 16; ++j) pn[j] = 0.f;
#pragma unroll
        for (int k = 0; k < 60; ++k) {
            const float xv = x[k];
#pragma unroll
            for (int j = 0; j < 8; ++j)  pes[j] = fmaf(xv, accL[j * 60 + k], pes[j]);
#pragma unroll
            for (int j = 0; j < 16; ++j) pn[j]  = fmaf(xv, accL[480 + j * 60 + k], pn[j]);
        }
        store_h8(&sprojH[v * 8], pes);
        store_h16(&n1H[v * 16], pn);
    }
    __syncthreads();

    // ---- P1.5: zero accL ----
    for (int i = tid; i < 14400; i += 512) accL[i] = 0.f;
    __syncthreads();

    // ---- P2: encoder edge pass -> segment sums + counts + edge-sum ----
    {
        float wee[8], bb[8], es[8];
#pragma unroll
        for (int j = 0; j < 8; ++j) { wee[j] = eWee[j]; bb[j] = ebe[j]; es[j] = 0.f; }
        const int ebase = g * EPG;
        for (int t = tid; t < EPG; t += 512) {
            const int e = ebase + t;
            const float f = ef[e];
            const int s = snd[e] - g * NPG;
            const int r = rcv[e] - g * NPG;
            float ps[8]; load_h8(&sprojH[s * 8], ps);
#pragma unroll
            for (int j = 0; j < 8; ++j) {
                const float v = fmaxf(0.f, fmaf(f, wee[j], ps[j] + bb[j]));
                atomicAdd(&accL[r * 9 + j], v);
                es[j] += v;
            }
            atomicAdd(&accL[r * 9 + 8], 1.f);
        }
#pragma unroll
        for (int j = 0; j < 8; ++j) {
            float v = es[j];
#pragma unroll
            for (int o = 32; o >= 1; o >>= 1) v += __shfl_xor(v, o);
            if ((tid & 63) == 0) atomicAdd(&red[R_ES1 + j], v);
        }
    }
    __syncthreads();

    // ---- P3: encoder node pass -> n1 (in place), pes2, node-sum ----
    {
        float bn16[16];
#pragma unroll
        for (int j = 0; j < 16; ++j) bn16[j] = ebn[j];
        float ns[16];
#pragma unroll
        for (int j = 0; j < 16; ++j) ns[j] = 0.f;
        for (int v = tid; v < NPG; v += 512) {
            const float ic = 1.f / fmaxf(accL[v * 9 + 8], 1.f);
            float m[8];
#pragma unroll
            for (int j = 0; j < 8; ++j) m[j] = accL[v * 9 + j] * ic;
            float pn[16]; load_h16(&n1H[v * 16], pn);
            float n1[16];
#pragma unroll
            for (int j = 0; j < 16; ++j) {
                float x = pn[j] + bn16[j];
#pragma unroll
                for (int k = 0; k < 8; ++k) x = fmaf(m[k], wLDS[W_ENI + j * 8 + k], x);
                n1[j] = fmaxf(0.f, x);
                ns[j] += n1[j];
            }
            store_h16(&n1H[v * 16], n1);
            float p2[8];
#pragma unroll
            for (int o = 0; o < 8; ++o) {
                float x = 0.f;
#pragma unroll
                for (int k = 0; k < 16; ++k) x = fmaf(n1[k], wLDS[W_HES + o * 16 + k], x);
                p2[o] = x;
            }
            store_h8(&pes2H[v * 8], p2);
        }
#pragma unroll
        for (int j = 0; j < 16; ++j) {
            float v = ns[j];
#pragma unroll
            for (int o = 32; o >= 1; o >>= 1) v += __shfl_xor(v, o);
            if ((tid & 63) == 0) atomicAdd(&red[R_NS1 + j], v);
        }
    }
    __syncthreads();

    // ---- P4: encoder global layer; project g1 for hidden layers ----
    if (tid < 4) {
        const int o = tid;
        float x = ebg[o];
#pragma unroll
        for (int k = 0; k < 8; ++k)  x = fmaf(red[R_ES1 + k] * (1.f / EPG), eWge[o * 8 + k], x);
#pragma unroll
        for (int k = 0; k < 16; ++k) x = fmaf(red[R_NS1 + k] * (1.f / NPG), eWgn[o * 16 + k], x);
        red[R_G1 + o] = fmaxf(0.f, x);
    }
    __syncthreads();
    if (tid < 8) {
        float x = hbe[tid];
#pragma unroll
        for (int o = 0; o < 4; ++o) x = fmaf(red[R_G1 + o], hWeg[tid * 4 + o], x);
        red[R_GPE + tid] = x;
    } else if (tid < 24) {
        const int j = tid - 8;
        float x = hbn[j];
#pragma unroll
        for (int o = 0; o < 4; ++o) x = fmaf(red[R_G1 + o], hWng[j * 4 + o], x);
        red[R_GPN + j] = x;
    }
    __syncthreads();
    // re-zero acc slots 0..7 (keep counts in slot 8)
    for (int i = tid; i < 12800; i += 512) accL[(i >> 3) * 9 + (i & 7)] = 0.f;
    __syncthreads();

    // ---- P5: hidden edge pass (recompute e1) -> segment sums + edge-sum ----
    {
        float wee[8], bb[8], add2[8], es2[8];
#pragma unroll
        for (int j = 0; j < 8; ++j) { wee[j] = eWee[j]; bb[j] = ebe[j]; add2[j] = red[R_GPE + j]; es2[j] = 0.f; }
        float w2[64];
#pragma unroll
        for (int j = 0; j < 64; ++j) w2[j] = wLDS[W_HEE + j];
        const int ebase = g * EPG;
        for (int t = tid; t < EPG; t += 512) {
            const int e = ebase + t;
            const float f = ef[e];
            const int s = snd[e] - g * NPG;
            const int r = rcv[e] - g * NPG;
            float ps[8]; load_h8(&sprojH[s * 8], ps);
            float p2[8]; load_h8(&pes2H[s * 8], p2);
            float e1[8];
#pragma unroll
            for (int j = 0; j < 8; ++j) e1[j] = fmaxf(0.f, fmaf(f, wee[j], ps[j] + bb[j]));
#pragma unroll
            for (int j = 0; j < 8; ++j) {
                float v = p2[j] + add2[j];
#pragma unroll
                for (int k = 0; k < 8; ++k) v = fmaf(e1[k], w2[j * 8 + k], v);
                v = fmaxf(0.f, v);
                atomicAdd(&accL[r * 9 + j], v);
                es2[j] += v;
            }
        }
#pragma unroll
        for (int j = 0; j < 8; ++j) {
            float v = es2[j];
#pragma unroll
            for (int o = 32; o >= 1; o >>= 1) v += __shfl_xor(v, o);
            if ((tid & 63) == 0) atomicAdd(&red[R_ES2 + j], v);
        }
    }
    __syncthreads();

    // ---- P6: hidden node pass + node readout + node-sum ----
    {
        float gpn16[16], rw[16];
#pragma unroll
        for (int j = 0; j < 16; ++j) { gpn16[j] = red[R_GPN + j]; rw[j] = roWn[j]; }
        const float rb = robn[0];
        float ns2[16];
#pragma unroll
        for (int j = 0; j < 16; ++j) ns2[j] = 0.f;
        for (int v = tid; v < NPG; v += 512) {
            const float ic = 1.f / fmaxf(accL[v * 9 + 8], 1.f);
            float m[8];
#pragma unroll
            for (int j = 0; j < 8; ++j) m[j] = accL[v * 9 + j] * ic;
            float n1[16]; load_h16(&n1H[v * 16], n1);
            float z = rb;
#pragma unroll
            for (int j = 0; j < 16; ++j) {
                float x = gpn16[j];
#pragma unroll
                for (int k = 0; k < 16; ++k) x = fmaf(n1[k], wLDS[W_HNN + j * 16 + k], x);
#pragma unroll
                for (int k = 0; k < 8; ++k)  x = fmaf(m[k], wLDS[W_HNI + j * 8 + k], x);
                const float n2 = fmaxf(0.f, x);
                ns2[j] += n2;
                z = fmaf(n2, rw[j], z);
            }
            outn[g * NPG + v] = 1.f / (1.f + expf(-z));
        }
#pragma unroll
        for (int j = 0; j < 16; ++j) {
            float v = ns2[j];
#pragma unroll
            for (int o = 32; o >= 1; o >>= 1) v += __shfl_xor(v, o);
            if ((tid & 63) == 0) atomicAdd(&red[R_NS2 + j], v);
        }
    }
    __syncthreads();

    // ---- P7: hidden global layer + global readout ----
    if (tid < 4) {
        const int o = tid;
        float x = hbg[o];
#pragma unroll
        for (int k = 0; k < 8; ++k)  x = fmaf(red[R_ES2 + k] * (1.f / EPG), hWge[o * 8 + k], x);
#pragma unroll
        for (int k = 0; k < 16; ++k) x = fmaf(red[R_NS2 + k] * (1.f / NPG), hWgn[o * 16 + k], x);
#pragma unroll
        for (int k = 0; k < 4; ++k)  x = fmaf(red[R_G1 + k], hWgg[o * 4 + k], x);
        red[R_G2 + o] = fmaxf(0.f, x);
    }
    __syncthreads();
    if (tid == 0) {
        float z = robg[0];
#pragma unroll
        for (int o = 0; o < 4; ++o) z = fmaf(red[R_G2 + o], roWg[o], z);
        outg[g] = 1.f / (1.f + expf(-z));
    }
}

extern "C" void kernel_launch(void* const* d_in, const int* in_sizes, int n_in,
                              void* d_out, int out_size, void* d_ws, size_t ws_size,
                              hipStream_t stream)
{
    const float* nf   = (const float*)d_in[0];
    const float* ef   = (const float*)d_in[1];
    const int*   snd  = (const int*)d_in[2];
    const int*   rcv  = (const int*)d_in[3];
    const float* eWee = (const float*)d_in[6];
    const float* eWes = (const float*)d_in[7];
    const float* ebe  = (const float*)d_in[8];
    const float* eWnn = (const float*)d_in[9];
    const float* eWni = (const float*)d_in[10];
    const float* ebn  = (const float*)d_in[11];
    const float* eWge = (const float*)d_in[12];
    const float* eWgn = (const float*)d_in[13];
    const float* ebg  = (const float*)d_in[14];
    const float* hWee = (const float*)d_in[15];
    const float* hWes = (const float*)d_in[16];
    const float* hWeg = (const float*)d_in[17];
    const float* hbe  = (const float*)d_in[18];
    const float* hWnn = (const float*)d_in[19];
    const float* hWni = (const float*)d_in[20];
    const float* hWng = (const float*)d_in[21];
    const float* hbn  = (const float*)d_in[22];
    const float* hWge = (const float*)d_in[23];
    const float* hWgn = (const float*)d_in[24];
    const float* hWgg = (const float*)d_in[25];
    const float* hbg  = (const float*)d_in[26];
    const float* roWn = (const float*)d_in[27];
    const float* robn = (const float*)d_in[28];
    const float* roWg = (const float*)d_in[29];
    const float* robg = (const float*)d_in[30];

    float* out = (float*)d_out;

    gn_fused<<<NG, 512, 0, stream>>>(
        nf, ef, snd, rcv,
        eWee, eWes, ebe, eWnn, eWni, ebn, eWge, eWgn, ebg,
        hWee, hWes, hWeg, hbe, hWnn, hWni, hWng, hbn,
        hWge, hWgn, hWgg, hbg, roWn, robn, roWg, robg,
        out, out + NN);
}

// Round 5
// 275.444 us; speedup vs baseline: 3.0824x; 3.0824x over previous
//
#include <hip/hip_runtime.h>
#include <hip/hip_bf16.h>

#define NN   102400
#define NG   64
#define NPG  1600
#define NE   1638400
#define EPG  25600
#define BPG  4
#define EPB  (EPG / BPG)

// workspace layout (float offsets) — total 41*NN + 4864 floats ≈ 16.8 MB (proven to fit in R1)
#define OFF_SPROJ 0            // [NN][16]: slots 0..8 = enc p_es (K1), 8..16 = hid pes2 (K3)
#define OFF_PNN   (16 * NN)    // [NN][16]: enc p_nn (K1), overwritten with n1@hWnn^T (K3)
#define OFF_ACC   (32 * NN)    // [NN][8]: segment sums (reused acc1 then acc2)
#define OFF_CNT   (40 * NN)    // [NN]: in-degree (float)
#define OFF_GS    (41 * NN)
#define GS_ESUM1 0     // G*8
#define GS_NSUM1 512   // G*16
#define GS_ESUM2 1536  // G*8
#define GS_NSUM2 2048  // G*16
#define GS_G1    3072  // G*4
#define GS_GPE   3328  // G*8  (g1@hWeg^T, excl hbe)
#define GS_GPN   3840  // G*16 (g1@hWng^T, excl hbn)

__device__ __forceinline__ float sigmoidf_(float x) { return 1.f / (1.f + expf(-x)); }

// K1: per-node pre-projections of raw node features.
__global__ __launch_bounds__(256) void k_node_pre(
    const float* __restrict__ nf,
    const float* __restrict__ Wes,   // [8][60]
    const float* __restrict__ Wnn,   // [16][60]
    float* __restrict__ sproj,       // [NN][16]
    float* __restrict__ pnn)         // [NN][16]
{
    __shared__ float wE[480], wN[960];
    for (int i = threadIdx.x; i < 480; i += 256) wE[i] = Wes[i];
    for (int i = threadIdx.x; i < 960; i += 256) wN[i] = Wnn[i];
    __syncthreads();
    const int v = blockIdx.x * 256 + threadIdx.x;
    const float4* row = reinterpret_cast<const float4*>(nf + (size_t)v * 60);
    float x[60];
#pragma unroll
    for (int i = 0; i < 15; ++i) {
        const float4 a = row[i];
        x[4 * i] = a.x; x[4 * i + 1] = a.y; x[4 * i + 2] = a.z; x[4 * i + 3] = a.w;
    }
    float pes[8], pn[16];
#pragma unroll
    for (int j = 0; j < 8; ++j) pes[j] = 0.f;
#pragma unroll
    for (int j = 0; j < 16; ++j) pn[j] = 0.f;
#pragma unroll
    for (int k = 0; k < 60; ++k) {
        const float xv = x[k];
#pragma unroll
        for (int j = 0; j < 8; ++j)  pes[j] = fmaf(xv, wE[j * 60 + k], pes[j]);
#pragma unroll
        for (int j = 0; j < 16; ++j) pn[j]  = fmaf(xv, wN[j * 60 + k], pn[j]);
    }
    float4* sp = reinterpret_cast<float4*>(sproj + (size_t)v * 16);
    sp[0] = make_float4(pes[0], pes[1], pes[2], pes[3]);
    sp[1] = make_float4(pes[4], pes[5], pes[6], pes[7]);
    float4* pp = reinterpret_cast<float4*>(pnn + (size_t)v * 16);
    pp[0] = make_float4(pn[0], pn[1], pn[2], pn[3]);
    pp[1] = make_float4(pn[4], pn[5], pn[6], pn[7]);
    pp[2] = make_float4(pn[8], pn[9], pn[10], pn[11]);
    pp[3] = make_float4(pn[12], pn[13], pn[14], pn[15]);
}

// K2: encoder edge layer -> LDS segment-sum over receivers, merge via global atomics.
__global__ __launch_bounds__(512) void k_enc_edge(
    const float* __restrict__ ef, const int* __restrict__ snd,
    const int* __restrict__ rcv, const float* __restrict__ sproj,
    const float* __restrict__ Wee, const float* __restrict__ be,
    float* __restrict__ acc, float* __restrict__ cnt,
    float* __restrict__ esum)
{
    __shared__ float accL[NPG * 9];
    const int g = blockIdx.x / BPG;
    const int c = blockIdx.x % BPG;
    for (int i = threadIdx.x; i < NPG * 9; i += 512) accL[i] = 0.f;
    float wee[8], bb[8], es[8];
#pragma unroll
    for (int j = 0; j < 8; ++j) { wee[j] = Wee[j]; bb[j] = be[j]; es[j] = 0.f; }
    __syncthreads();
    const int base = g * EPG + c * EPB;
    for (int t = threadIdx.x; t < EPB; t += 512) {
        const int e = base + t;
        const float f = ef[e];
        const int s = snd[e];
        const int rl = rcv[e] - g * NPG;
        const float4* sp = reinterpret_cast<const float4*>(sproj + (size_t)s * 16);
        const float4 p0 = sp[0], p1 = sp[1];
        const float pv[8] = {p0.x, p0.y, p0.z, p0.w, p1.x, p1.y, p1.z, p1.w};
#pragma unroll
        for (int j = 0; j < 8; ++j) {
            const float v = fmaxf(0.f, fmaf(f, wee[j], pv[j] + bb[j]));
            atomicAdd(&accL[rl * 9 + j], v);
            es[j] += v;
        }
        atomicAdd(&accL[rl * 9 + 8], 1.f);
    }
    __syncthreads();
    for (int i = threadIdx.x; i < NPG * 9; i += 512) {
        const float v = accL[i];
        if (v != 0.f) {
            const int l = i / 9, j = i - l * 9;
            if (j < 8) atomicAdd(&acc[((size_t)(g * NPG + l)) * 8 + j], v);
            else       atomicAdd(&cnt[g * NPG + l], v);
        }
    }
#pragma unroll
    for (int j = 0; j < 8; ++j) {
        float v = es[j];
#pragma unroll
        for (int o = 32; o >= 1; o >>= 1) v += __shfl_xor(v, o);
        if ((threadIdx.x & 63) == 0) atomicAdd(&esum[g * 8 + j], v);
    }
}

// K3: encoder node layer + pre-projections for hidden layer + per-graph node sum.
__global__ __launch_bounds__(320) void k_enc_node(
    const float* __restrict__ acc, const float* __restrict__ cnt,
    float* __restrict__ pnn,       // in: enc p_nn, out: n1 @ hWnn^T
    float* __restrict__ sproj,     // write slots 8..16 (n1 @ hWes^T)
    const float* __restrict__ Wni, const float* __restrict__ bn,
    const float* __restrict__ hWes, const float* __restrict__ hWnn,
    float* __restrict__ nsum)
{
    __shared__ float wNI[128], wES[128], wNN2[256], bN[16];
    for (int i = threadIdx.x; i < 128; i += 320) { wNI[i] = Wni[i]; wES[i] = hWes[i]; }
    for (int i = threadIdx.x; i < 256; i += 320) wNN2[i] = hWnn[i];
    if (threadIdx.x < 16) bN[threadIdx.x] = bn[threadIdx.x];
    __syncthreads();
    const int v = blockIdx.x * 320 + threadIdx.x;
    const int g = blockIdx.x / 5;
    const float4* av = reinterpret_cast<const float4*>(acc + (size_t)v * 8);
    const float4 a0 = av[0], a1 = av[1];
    const float ic = 1.f / fmaxf(cnt[v], 1.f);
    const float m[8] = {a0.x * ic, a0.y * ic, a0.z * ic, a0.w * ic,
                        a1.x * ic, a1.y * ic, a1.z * ic, a1.w * ic};
    const float4* pv4 = reinterpret_cast<const float4*>(pnn + (size_t)v * 16);
    const float4 q0 = pv4[0], q1 = pv4[1], q2 = pv4[2], q3 = pv4[3];
    const float p[16] = {q0.x, q0.y, q0.z, q0.w, q1.x, q1.y, q1.z, q1.w,
                         q2.x, q2.y, q2.z, q2.w, q3.x, q3.y, q3.z, q3.w};
    float n1[16];
#pragma unroll
    for (int j = 0; j < 16; ++j) {
        float x = p[j] + bN[j];
#pragma unroll
        for (int k = 0; k < 8; ++k) x = fmaf(m[k], wNI[j * 8 + k], x);
        n1[j] = fmaxf(0.f, x);
    }
    float pe[8];
#pragma unroll
    for (int o = 0; o < 8; ++o) {
        float x = 0.f;
#pragma unroll
        for (int j = 0; j < 16; ++j) x = fmaf(n1[j], wES[o * 16 + j], x);
        pe[o] = x;
    }
    float4* spw = reinterpret_cast<float4*>(sproj + (size_t)v * 16 + 8);
    spw[0] = make_float4(pe[0], pe[1], pe[2], pe[3]);
    spw[1] = make_float4(pe[4], pe[5], pe[6], pe[7]);
    float pw[16];
#pragma unroll
    for (int o = 0; o < 16; ++o) {
        float x = 0.f;
#pragma unroll
        for (int j = 0; j < 16; ++j) x = fmaf(n1[j], wNN2[o * 16 + j], x);
        pw[o] = x;
    }
    float4* pp = reinterpret_cast<float4*>(pnn + (size_t)v * 16);
    pp[0] = make_float4(pw[0], pw[1], pw[2], pw[3]);
    pp[1] = make_float4(pw[4], pw[5], pw[6], pw[7]);
    pp[2] = make_float4(pw[8], pw[9], pw[10], pw[11]);
    pp[3] = make_float4(pw[12], pw[13], pw[14], pw[15]);
#pragma unroll
    for (int j = 0; j < 16; ++j) {
        float x = n1[j];
#pragma unroll
        for (int o = 32; o >= 1; o >>= 1) x += __shfl_xor(x, o);
        if ((threadIdx.x & 63) == 0) atomicAdd(&nsum[g * 16 + j], x);
    }
}

// K4: encoder global layer + projections of g1 used by hidden edge/node layers.
__global__ void k_glob_enc(
    const float* __restrict__ esum1, const float* __restrict__ nsum1,
    const float* __restrict__ Wge, const float* __restrict__ Wgn,
    const float* __restrict__ bg,
    const float* __restrict__ hWeg, const float* __restrict__ hWng,
    float* __restrict__ g1, float* __restrict__ gpe, float* __restrict__ gpn)
{
    const int g = threadIdx.x;
    if (g >= NG) return;
    float gv[4];
#pragma unroll
    for (int o = 0; o < 4; ++o) {
        float x = bg[o];
#pragma unroll
        for (int k = 0; k < 8; ++k)  x = fmaf(esum1[g * 8 + k] * (1.f / EPG), Wge[o * 8 + k], x);
#pragma unroll
        for (int k = 0; k < 16; ++k) x = fmaf(nsum1[g * 16 + k] * (1.f / NPG), Wgn[o * 16 + k], x);
        gv[o] = fmaxf(0.f, x);
        g1[g * 4 + o] = gv[o];
    }
#pragma unroll
    for (int j = 0; j < 8; ++j) {
        float x = 0.f;
#pragma unroll
        for (int o = 0; o < 4; ++o) x = fmaf(gv[o], hWeg[j * 4 + o], x);
        gpe[g * 8 + j] = x;
    }
#pragma unroll
    for (int j = 0; j < 16; ++j) {
        float x = 0.f;
#pragma unroll
        for (int o = 0; o < 4; ++o) x = fmaf(gv[o], hWng[j * 4 + o], x);
        gpn[g * 16 + j] = x;
    }
}

// K5: hidden edge layer (recomputes e1 on the fly) -> segment sums.
__global__ __launch_bounds__(512) void k_hid_edge(
    const float* __restrict__ ef, const int* __restrict__ snd,
    const int* __restrict__ rcv, const float* __restrict__ sproj,
    const float* __restrict__ eWee, const float* __restrict__ ebe,
    const float* __restrict__ hWee, const float* __restrict__ hbe,
    const float* __restrict__ gpe,
    float* __restrict__ acc, float* __restrict__ esum)
{
    __shared__ float accL[NPG * 9];
    const int g = blockIdx.x / BPG;
    const int c = blockIdx.x % BPG;
    for (int i = threadIdx.x; i < NPG * 9; i += 512) accL[i] = 0.f;
    float wee[8], bb[8], add2[8], es2[8], w2[64];
#pragma unroll
    for (int j = 0; j < 8; ++j) {
        wee[j] = eWee[j]; bb[j] = ebe[j];
        add2[j] = gpe[g * 8 + j] + hbe[j]; es2[j] = 0.f;
    }
#pragma unroll
    for (int j = 0; j < 64; ++j) w2[j] = hWee[j];
    __syncthreads();
    const int base = g * EPG + c * EPB;
    for (int t = threadIdx.x; t < EPB; t += 512) {
        const int e = base + t;
        const float f = ef[e];
        const int s = snd[e];
        const int rl = rcv[e] - g * NPG;
        const float4* sp = reinterpret_cast<const float4*>(sproj + (size_t)s * 16);
        const float4 p0 = sp[0], p1 = sp[1], p2 = sp[2], p3 = sp[3];
        const float pv[8] = {p0.x, p0.y, p0.z, p0.w, p1.x, p1.y, p1.z, p1.w};
        const float qv[8] = {p2.x, p2.y, p2.z, p2.w, p3.x, p3.y, p3.z, p3.w};
        float e1[8];
#pragma unroll
        for (int j = 0; j < 8; ++j) e1[j] = fmaxf(0.f, fmaf(f, wee[j], pv[j] + bb[j]));
#pragma unroll
        for (int j = 0; j < 8; ++j) {
            float v = qv[j] + add2[j];
#pragma unroll
            for (int k = 0; k < 8; ++k) v = fmaf(e1[k], w2[j * 8 + k], v);
            v = fmaxf(0.f, v);
            atomicAdd(&accL[rl * 9 + j], v);
            es2[j] += v;
        }
    }
    __syncthreads();
    for (int i = threadIdx.x; i < NPG * 9; i += 512) {
        const float v = accL[i];
        const int l = i / 9, j = i - l * 9;
        if (j < 8 && v != 0.f)
            atomicAdd(&acc[((size_t)(g * NPG + l)) * 8 + j], v);
    }
#pragma unroll
    for (int j = 0; j < 8; ++j) {
        float v = es2[j];
#pragma unroll
        for (int o = 32; o >= 1; o >>= 1) v += __shfl_xor(v, o);
        if ((threadIdx.x & 63) == 0) atomicAdd(&esum[g * 8 + j], v);
    }
}

// K6: hidden node layer + node readout + per-graph node sum.
__global__ __launch_bounds__(320) void k_hid_node(
    const float* __restrict__ acc, const float* __restrict__ cnt,
    const float* __restrict__ pnn,   // n1 @ hWnn^T
    const float* __restrict__ hWni, const float* __restrict__ hbn,
    const float* __restrict__ gpn,
    const float* __restrict__ roWn, const float* __restrict__ robn,
    float* __restrict__ nsum, float* __restrict__ outn)
{
    __shared__ float wNI[128], bN[16], rW[16];
    for (int i = threadIdx.x; i < 128; i += 320) wNI[i] = hWni[i];
    if (threadIdx.x < 16) { bN[threadIdx.x] = hbn[threadIdx.x]; rW[threadIdx.x] = roWn[threadIdx.x]; }
    __syncthreads();
    const int v = blockIdx.x * 320 + threadIdx.x;
    const int g = blockIdx.x / 5;
    const float4* av = reinterpret_cast<const float4*>(acc + (size_t)v * 8);
    const float4 a0 = av[0], a1 = av[1];
    const float ic = 1.f / fmaxf(cnt[v], 1.f);
    const float m[8] = {a0.x * ic, a0.y * ic, a0.z * ic, a0.w * ic,
                        a1.x * ic, a1.y * ic, a1.z * ic, a1.w * ic};
    const float4* pv4 = reinterpret_cast<const float4*>(pnn + (size_t)v * 16);
    const float4 q0 = pv4[0], q1 = pv4[1], q2 = pv4[2], q3 = pv4[3];
    const float p[16] = {q0.x, q0.y, q0.z, q0.w, q1.x, q1.y, q1.z, q1.w,
                         q2.x, q2.y, q2.z, q2.w, q3.x, q3.y, q3.z, q3.w};
    float z = robn[0];
    float n2[16];
#pragma unroll
    for (int j = 0; j < 16; ++j) {
        float x = p[j] + gpn[g * 16 + j] + bN[j];
#pragma unroll
        for (int k = 0; k < 8; ++k) x = fmaf(m[k], wNI[j * 8 + k], x);
        n2[j] = fmaxf(0.f, x);
        z = fmaf(n2[j], rW[j], z);
    }
    outn[v] = sigmoidf_(z);
#pragma unroll
    for (int j = 0; j < 16; ++j) {
        float x = n2[j];
#pragma unroll
        for (int o = 32; o >= 1; o >>= 1) x += __shfl_xor(x, o);
        if ((threadIdx.x & 63) == 0) atomicAdd(&nsum[g * 16 + j], x);
    }
}

// K7: hidden global layer + global readout.
__global__ void k_glob_hid(
    const float* __restrict__ esum2, const float* __restrict__ nsum2,
    const float* __restrict__ g1,
    const float* __restrict__ hWge, const float* __restrict__ hWgn,
    const float* __restrict__ hWgg, const float* __restrict__ hbg,
    const float* __restrict__ roWg, const float* __restrict__ robg,
    float* __restrict__ outg)
{
    const int g = threadIdx.x;
    if (g >= NG) return;
    float gv[4];
#pragma unroll
    for (int o = 0; o < 4; ++o) {
        float x = hbg[o];
#pragma unroll
        for (int k = 0; k < 8; ++k)  x = fmaf(esum2[g * 8 + k] * (1.f / EPG), hWge[o * 8 + k], x);
#pragma unroll
        for (int k = 0; k < 16; ++k) x = fmaf(nsum2[g * 16 + k] * (1.f / NPG), hWgn[o * 16 + k], x);
#pragma unroll
        for (int k = 0; k < 4; ++k)  x = fmaf(g1[g * 4 + k], hWgg[o * 4 + k], x);
        gv[o] = fmaxf(0.f, x);
    }
    float z = robg[0];
#pragma unroll
    for (int o = 0; o < 4; ++o) z = fmaf(gv[o], roWg[o], z);
    outg[g] = sigmoidf_(z);
}

extern "C" void kernel_launch(void* const* d_in, const int* in_sizes, int n_in,
                              void* d_out, int out_size, void* d_ws, size_t ws_size,
                              hipStream_t stream)
{
    const float* nf   = (const float*)d_in[0];
    const float* ef   = (const float*)d_in[1];
    const int*   snd  = (const int*)d_in[2];
    const int*   rcv  = (const int*)d_in[3];
    const float* eWee = (const float*)d_in[6];
    const float* eWes = (const float*)d_in[7];
    const float* ebe  = (const float*)d_in[8];
    const float* eWnn = (const float*)d_in[9];
    const float* eWni = (const float*)d_in[10];
    const float* ebn  = (const float*)d_in[11];
    const float* eWge = (const float*)d_in[12];
    const float* eWgn = (const float*)d_in[13];
    const float* ebg  = (const float*)d_in[14];
    const float* hWee = (const float*)d_in[15];
    const float* hWes = (const float*)d_in[16];
    const float* hWeg = (const float*)d_in[17];
    const float* hbe  = (const float*)d_in[18];
    const float* hWnn = (const float*)d_in[19];
    const float* hWni = (const float*)d_in[20];
    const float* hWng = (const float*)d_in[21];
    const float* hbn  = (const float*)d_in[22];
    const float* hWge = (const float*)d_in[23];
    const float* hWgn = (const float*)d_in[24];
    const float* hWgg = (const float*)d_in[25];
    const float* hbg  = (const float*)d_in[26];
    const float* roWn = (const float*)d_in[27];
    const float* robn = (const float*)d_in[28];
    const float* roWg = (const float*)d_in[29];
    const float* robg = (const float*)d_in[30];

    float* ws    = (float*)d_ws;
    float* sproj = ws + OFF_SPROJ;
    float* pnn   = ws + OFF_PNN;
    float* acc   = ws + OFF_ACC;
    float* cnt   = ws + OFF_CNT;
    float* gs    = ws + OFF_GS;
    float* esum1 = gs + GS_ESUM1;
    float* nsum1 = gs + GS_NSUM1;
    float* esum2 = gs + GS_ESUM2;
    float* nsum2 = gs + GS_NSUM2;
    float* g1    = gs + GS_G1;
    float* gpe   = gs + GS_GPE;
    float* gpn   = gs + GS_GPN;
    float* out   = (float*)d_out;

    // zero acc + cnt + esum1/nsum1/esum2/nsum2 (contiguous)
    hipMemsetAsync(acc, 0, (size_t)(9 * NN + 3072) * sizeof(float), stream);

    k_node_pre<<<NN / 256, 256, 0, stream>>>(nf, eWes, eWnn, sproj, pnn);
    k_enc_edge<<<NG * BPG, 512, 0, stream>>>(ef, snd, rcv, sproj, eWee, ebe, acc, cnt, esum1);
    k_enc_node<<<NN / 320, 320, 0, stream>>>(acc, cnt, pnn, sproj, eWni, ebn, hWes, hWnn, nsum1);
    k_glob_enc<<<1, 64, 0, stream>>>(esum1, nsum1, eWge, eWgn, ebg, hWeg, hWng, g1, gpe, gpn);
    hipMemsetAsync(acc, 0, (size_t)(8 * NN) * sizeof(float), stream);
    k_hid_edge<<<NG * BPG, 512, 0, stream>>>(ef, snd, rcv, sproj, eWee, ebe, hWee, hbe, gpe, acc, esum2);
    k_hid_node<<<NN / 320, 320, 0, stream>>>(acc, cnt, pnn, hWni, hbn, gpn, roWn, robn, nsum2, out);
    k_glob_hid<<<1, 64, 0, stream>>>(esum2, nsum2, g1, hWge, hWgn, hWgg, hbg, roWg, robg, out + NN);
}

// Round 6
// 189.279 us; speedup vs baseline: 4.4856x; 1.4552x over previous
//
#include <hip/hip_runtime.h>
#include <hip/hip_bf16.h>
#include <hip/hip_fp16.h>

#define NN   102400
#define NG   64
#define NPG  1600
#define NE   1638400
#define EPG  25600

typedef unsigned int u32;
typedef unsigned short u16;

// ---- workspace layout (float offsets), total ~13.95 MB (< 16.8 MB proven safe) ----
#define OFF_EDAT  0                       // u32[NE]: (sender_local<<16) | bf16(ef)
#define OFF_SPROJ (NE)                    // __half[NN*16]: [0..8)=enc p_es, [8..16)=pes2
#define OFF_PNN   (NE + 8 * NN)           // __half[NN*16]: p_nn -> n1@hWnn^T
#define OFF_DEG   (NE + 16 * NN)          // int[NN]
#define OFF_GS    (NE + 17 * NN)          // sums etc (4864 floats)
#define OFF_CUR   (NE + 17 * NN + 4864)   // int[NN]
// gs offsets
#define GS_ESUM1 0     // G*8
#define GS_NSUM1 512   // G*16
#define GS_ESUM2 1536  // G*8
#define GS_NSUM2 2048  // G*16
#define GS_G1    3072  // G*4
#define GS_GPE   3328  // G*8
#define GS_GPN   3840  // G*16

struct H8 { __half2 a, b, c, d; };

__device__ __forceinline__ void unpack8(const H8 v, float* o) {
    float2 t0 = __half22float2(v.a), t1 = __half22float2(v.b);
    float2 t2 = __half22float2(v.c), t3 = __half22float2(v.d);
    o[0]=t0.x; o[1]=t0.y; o[2]=t1.x; o[3]=t1.y; o[4]=t2.x; o[5]=t2.y; o[6]=t3.x; o[7]=t3.y;
}
__device__ __forceinline__ H8 pack8(const float* v) {
    H8 r;
    r.a = __floats2half2_rn(v[0], v[1]); r.b = __floats2half2_rn(v[2], v[3]);
    r.c = __floats2half2_rn(v[4], v[5]); r.d = __floats2half2_rn(v[6], v[7]);
    return r;
}
__device__ __forceinline__ u16 f2bf(float f) {
    u32 u = __float_as_uint(f);
    return (u16)((u + 0x7fffu + ((u >> 16) & 1u)) >> 16);
}
__device__ __forceinline__ float wsum(float v) {
#pragma unroll
    for (int o = 32; o >= 1; o >>= 1) v += __shfl_xor(v, o);
    return v;
}
__device__ __forceinline__ float sigmoidf_(float x) { return 1.f / (1.f + expf(-x)); }

// H1: in-degree histogram (LDS-local per quarter-graph).
__global__ __launch_bounds__(512) void k_hist(const int* __restrict__ rcv, int* __restrict__ deg) {
    __shared__ int h[NPG];
    const int g = blockIdx.x >> 2, c = blockIdx.x & 3;
    for (int i = threadIdx.x; i < NPG; i += 512) h[i] = 0;
    __syncthreads();
    const int base = g * EPG + c * (EPG / 4);
    for (int t = threadIdx.x; t < EPG / 4; t += 512) atomicAdd(&h[rcv[base + t] - g * NPG], 1);
    __syncthreads();
    for (int i = threadIdx.x; i < NPG; i += 512) { const int v = h[i]; if (v) atomicAdd(&deg[g * NPG + i], v); }
}

// H2: per-graph exclusive prefix scan of degrees -> cur (scatter cursors).
__global__ __launch_bounds__(320) void k_scan(const int* __restrict__ deg, int* __restrict__ cur) {
    __shared__ int part[320];
    const int g = blockIdx.x, tid = threadIdx.x;
    const int base = g * NPG + tid * 5;
    const int l0 = deg[base], l1 = deg[base + 1], l2 = deg[base + 2], l3 = deg[base + 3], l4 = deg[base + 4];
    const int p1 = l0, p2 = p1 + l1, p3 = p2 + l2, p4 = p3 + l3, ts = p4 + l4;
    part[tid] = ts;
    __syncthreads();
    for (int o = 1; o < 320; o <<= 1) {
        const int v = (tid >= o) ? part[tid - o] : 0;
        __syncthreads();
        part[tid] += v;
        __syncthreads();
    }
    const int off = g * EPG + part[tid] - ts;
    cur[base] = off; cur[base + 1] = off + p1; cur[base + 2] = off + p2;
    cur[base + 3] = off + p3; cur[base + 4] = off + p4;
}

// H3: scatter edge payloads into receiver-sorted order.
__global__ __launch_bounds__(256) void k_scatter(
    const float* __restrict__ ef, const int* __restrict__ snd, const int* __restrict__ rcv,
    int* __restrict__ cur, u32* __restrict__ edat)
{
    const int e = blockIdx.x * 256 + threadIdx.x;
    const int g = e / EPG;
    const int p = atomicAdd(&cur[rcv[e]], 1);
    const u32 s = (u32)(snd[e] - g * NPG);
    edat[p] = (s << 16) | (u32)f2bf(ef[e]);
}

// K1: per-node encoder pre-projections (f32 in, f16 out).
__global__ __launch_bounds__(256) void k_node_pre(
    const float* __restrict__ nf,
    const float* __restrict__ Wes,   // [8][60]
    const float* __restrict__ Wnn,   // [16][60]
    __half* __restrict__ sproj, __half* __restrict__ pnn)
{
    __shared__ float wE[480], wN[960];
    for (int i = threadIdx.x; i < 480; i += 256) wE[i] = Wes[i];
    for (int i = threadIdx.x; i < 960; i += 256) wN[i] = Wnn[i];
    __syncthreads();
    const int v = blockIdx.x * 256 + threadIdx.x;
    const float4* row = reinterpret_cast<const float4*>(nf + (size_t)v * 60);
    float x[60];
#pragma unroll
    for (int i = 0; i < 15; ++i) {
        const float4 a = row[i];
        x[4 * i] = a.x; x[4 * i + 1] = a.y; x[4 * i + 2] = a.z; x[4 * i + 3] = a.w;
    }
    float pes[8], pn[16];
#pragma unroll
    for (int j = 0; j < 8; ++j) pes[j] = 0.f;
#pragma unroll
    for (int j = 0; j < 16; ++j) pn[j] = 0.f;
#pragma unroll
    for (int k = 0; k < 60; ++k) {
        const float xv = x[k];
#pragma unroll
        for (int j = 0; j < 8; ++j)  pes[j] = fmaf(xv, wE[j * 60 + k], pes[j]);
#pragma unroll
        for (int j = 0; j < 16; ++j) pn[j]  = fmaf(xv, wN[j * 60 + k], pn[j]);
    }
    H8* sp = reinterpret_cast<H8*>(sproj) + (size_t)v * 2;
    sp[0] = pack8(pes);
    H8* pp = reinterpret_cast<H8*>(pnn) + (size_t)v * 2;
    pp[0] = pack8(pn); pp[1] = pack8(pn + 8);
}

// K2: encoder edge (gather) + node layer + hidden pre-projections + graph sums.
__global__ __launch_bounds__(256) void k_enc(
    const int* __restrict__ deg, const int* __restrict__ cur, const u32* __restrict__ edat,
    __half* __restrict__ sproj, __half* __restrict__ pnn,
    const float* __restrict__ eWee, const float* __restrict__ ebe,
    const float* __restrict__ eWni, const float* __restrict__ ebn,
    const float* __restrict__ hWes, const float* __restrict__ hWnn,
    float* __restrict__ esum, float* __restrict__ nsum)
{
    __shared__ float wNI[128], wES[128], wNN2[256], bN[16];
    for (int i = threadIdx.x; i < 128; i += 256) { wNI[i] = eWni[i]; wES[i] = hWes[i]; }
    for (int i = threadIdx.x; i < 256; i += 256) wNN2[i] = hWnn[i];
    if (threadIdx.x < 16) bN[threadIdx.x] = ebn[threadIdx.x];
    __syncthreads();
    const int v = blockIdx.x * 256 + threadIdx.x;
    const int g = v / NPG;                       // wave-uniform (1600 % 64 == 0)
    float wee[8], bb[8];
#pragma unroll
    for (int j = 0; j < 8; ++j) { wee[j] = eWee[j]; bb[j] = ebe[j]; }
    const int dg = deg[v];
    const int st = cur[v] - dg;
    float m[8];
#pragma unroll
    for (int j = 0; j < 8; ++j) m[j] = 0.f;
    const H8* hb = reinterpret_cast<const H8*>(sproj) + (size_t)g * NPG * 2;
    for (int i = 0; i < dg; ++i) {
        const u32 w = edat[st + i];
        const float f = __uint_as_float((w & 0xffffu) << 16);
        const int s = (int)(w >> 16);
        float pv[8]; unpack8(hb[(size_t)s * 2], pv);
#pragma unroll
        for (int j = 0; j < 8; ++j) m[j] += fmaxf(0.f, fmaf(f, wee[j], pv[j] + bb[j]));
    }
#pragma unroll
    for (int j = 0; j < 8; ++j) {
        const float t = wsum(m[j]);
        if ((threadIdx.x & 63) == 0) atomicAdd(&esum[g * 8 + j], t);
    }
    const float ic = 1.f / fmaxf((float)dg, 1.f);
    float mk[8];
#pragma unroll
    for (int k = 0; k < 8; ++k) mk[k] = m[k] * ic;
    const H8* pp = reinterpret_cast<const H8*>(pnn) + (size_t)v * 2;
    float pn[16]; unpack8(pp[0], pn); unpack8(pp[1], pn + 8);
    float n1[16];
#pragma unroll
    for (int j = 0; j < 16; ++j) {
        float x = pn[j] + bN[j];
#pragma unroll
        for (int k = 0; k < 8; ++k) x = fmaf(mk[k], wNI[j * 8 + k], x);
        n1[j] = fmaxf(0.f, x);
    }
    float pe[8];
#pragma unroll
    for (int o = 0; o < 8; ++o) {
        float x = 0.f;
#pragma unroll
        for (int j = 0; j < 16; ++j) x = fmaf(n1[j], wES[o * 16 + j], x);
        pe[o] = x;
    }
    H8* spw = reinterpret_cast<H8*>(sproj) + (size_t)v * 2;
    spw[1] = pack8(pe);
    float pw[16];
#pragma unroll
    for (int o = 0; o < 16; ++o) {
        float x = 0.f;
#pragma unroll
        for (int j = 0; j < 16; ++j) x = fmaf(n1[j], wNN2[o * 16 + j], x);
        pw[o] = x;
    }
    H8* ppw = reinterpret_cast<H8*>(pnn) + (size_t)v * 2;
    ppw[0] = pack8(pw); ppw[1] = pack8(pw + 8);
#pragma unroll
    for (int j = 0; j < 16; ++j) {
        const float t = wsum(n1[j]);
        if ((threadIdx.x & 63) == 0) atomicAdd(&nsum[g * 16 + j], t);
    }
}

// K3: encoder global layer + g1 projections for hidden layers.
__global__ void k_glob_enc(
    const float* __restrict__ esum1, const float* __restrict__ nsum1,
    const float* __restrict__ Wge, const float* __restrict__ Wgn, const float* __restrict__ bg,
    const float* __restrict__ hWeg, const float* __restrict__ hWng,
    float* __restrict__ g1, float* __restrict__ gpe, float* __restrict__ gpn)
{
    const int g = threadIdx.x;
    if (g >= NG) return;
    float gv[4];
#pragma unroll
    for (int o = 0; o < 4; ++o) {
        float x = bg[o];
#pragma unroll
        for (int k = 0; k < 8; ++k)  x = fmaf(esum1[g * 8 + k] * (1.f / EPG), Wge[o * 8 + k], x);
#pragma unroll
        for (int k = 0; k < 16; ++k) x = fmaf(nsum1[g * 16 + k] * (1.f / NPG), Wgn[o * 16 + k], x);
        gv[o] = fmaxf(0.f, x);
        g1[g * 4 + o] = gv[o];
    }
#pragma unroll
    for (int j = 0; j < 8; ++j) {
        float x = 0.f;
#pragma unroll
        for (int o = 0; o < 4; ++o) x = fmaf(gv[o], hWeg[j * 4 + o], x);
        gpe[g * 8 + j] = x;
    }
#pragma unroll
    for (int j = 0; j < 16; ++j) {
        float x = 0.f;
#pragma unroll
        for (int o = 0; o < 4; ++o) x = fmaf(gv[o], hWng[j * 4 + o], x);
        gpn[g * 16 + j] = x;
    }
}

// K4: hidden edge (recompute e1, gather) + node layer + readout + graph sums.
__global__ __launch_bounds__(256) void k_hid(
    const int* __restrict__ deg, const int* __restrict__ cur, const u32* __restrict__ edat,
    const __half* __restrict__ sproj, const __half* __restrict__ pnn,
    const float* __restrict__ eWee, const float* __restrict__ ebe,
    const float* __restrict__ hWee, const float* __restrict__ hbe, const float* __restrict__ gpe,
    const float* __restrict__ hWni, const float* __restrict__ hbn, const float* __restrict__ gpn,
    const float* __restrict__ roWn, const float* __restrict__ robn,
    float* __restrict__ esum, float* __restrict__ nsum, float* __restrict__ outn)
{
    __shared__ float w2[64], wNI[128], rW[16];
    for (int i = threadIdx.x; i < 128; i += 256) wNI[i] = hWni[i];
    if (threadIdx.x < 64) w2[threadIdx.x] = hWee[threadIdx.x];
    if (threadIdx.x < 16) rW[threadIdx.x] = roWn[threadIdx.x];
    __syncthreads();
    const int v = blockIdx.x * 256 + threadIdx.x;
    const int g = v / NPG;
    float wee[8], bb[8], add2[8];
#pragma unroll
    for (int j = 0; j < 8; ++j) { wee[j] = eWee[j]; bb[j] = ebe[j]; add2[j] = gpe[g * 8 + j] + hbe[j]; }
    const int dg = deg[v];
    const int st = cur[v] - dg;
    float m2[8];
#pragma unroll
    for (int j = 0; j < 8; ++j) m2[j] = 0.f;
    const H8* hb = reinterpret_cast<const H8*>(sproj) + (size_t)g * NPG * 2;
    for (int i = 0; i < dg; ++i) {
        const u32 w = edat[st + i];
        const float f = __uint_as_float((w & 0xffffu) << 16);
        const int s = (int)(w >> 16);
        float pv[8], qv[8];
        unpack8(hb[(size_t)s * 2], pv);
        unpack8(hb[(size_t)s * 2 + 1], qv);
        float e1[8];
#pragma unroll
        for (int j = 0; j < 8; ++j) e1[j] = fmaxf(0.f, fmaf(f, wee[j], pv[j] + bb[j]));
#pragma unroll
        for (int j = 0; j < 8; ++j) {
            float x = qv[j] + add2[j];
#pragma unroll
            for (int k = 0; k < 8; ++k) x = fmaf(e1[k], w2[j * 8 + k], x);
            m2[j] += fmaxf(0.f, x);
        }
    }
#pragma unroll
    for (int j = 0; j < 8; ++j) {
        const float t = wsum(m2[j]);
        if ((threadIdx.x & 63) == 0) atomicAdd(&esum[g * 8 + j], t);
    }
    const float ic = 1.f / fmaxf((float)dg, 1.f);
    float mk[8];
#pragma unroll
    for (int k = 0; k < 8; ++k) mk[k] = m2[k] * ic;
    const H8* pp = reinterpret_cast<const H8*>(pnn) + (size_t)v * 2;
    float pn[16]; unpack8(pp[0], pn); unpack8(pp[1], pn + 8);
    float z = robn[0];
    float n2[16];
#pragma unroll
    for (int j = 0; j < 16; ++j) {
        float x = pn[j] + gpn[g * 16 + j] + hbn[j];
#pragma unroll
        for (int k = 0; k < 8; ++k) x = fmaf(mk[k], wNI[j * 8 + k], x);
        n2[j] = fmaxf(0.f, x);
        z = fmaf(n2[j], rW[j], z);
    }
    outn[v] = sigmoidf_(z);
#pragma unroll
    for (int j = 0; j < 16; ++j) {
        const float t = wsum(n2[j]);
        if ((threadIdx.x & 63) == 0) atomicAdd(&nsum[g * 16 + j], t);
    }
}

// K5: hidden global layer + global readout.
__global__ void k_glob_hid(
    const float* __restrict__ esum2, const float* __restrict__ nsum2, const float* __restrict__ g1,
    const float* __restrict__ hWge, const float* __restrict__ hWgn,
    const float* __restrict__ hWgg, const float* __restrict__ hbg,
    const float* __restrict__ roWg, const float* __restrict__ robg,
    float* __restrict__ outg)
{
    const int g = threadIdx.x;
    if (g >= NG) return;
    float gv[4];
#pragma unroll
    for (int o = 0; o < 4; ++o) {
        float x = hbg[o];
#pragma unroll
        for (int k = 0; k < 8; ++k)  x = fmaf(esum2[g * 8 + k] * (1.f / EPG), hWge[o * 8 + k], x);
#pragma unroll
        for (int k = 0; k < 16; ++k) x = fmaf(nsum2[g * 16 + k] * (1.f / NPG), hWgn[o * 16 + k], x);
#pragma unroll
        for (int k = 0; k < 4; ++k)  x = fmaf(g1[g * 4 + k], hWgg[o * 4 + k], x);
        gv[o] = fmaxf(0.f, x);
    }
    float z = robg[0];
#pragma unroll
    for (int o = 0; o < 4; ++o) z = fmaf(gv[o], roWg[o], z);
    outg[g] = sigmoidf_(z);
}

extern "C" void kernel_launch(void* const* d_in, const int* in_sizes, int n_in,
                              void* d_out, int out_size, void* d_ws, size_t ws_size,
                              hipStream_t stream)
{
    const float* nf   = (const float*)d_in[0];
    const float* ef   = (const float*)d_in[1];
    const int*   snd  = (const int*)d_in[2];
    const int*   rcv  = (const int*)d_in[3];
    const float* eWee = (const float*)d_in[6];
    const float* eWes = (const float*)d_in[7];
    const float* ebe  = (const float*)d_in[8];
    const float* eWnn = (const float*)d_in[9];
    const float* eWni = (const float*)d_in[10];
    const float* ebn  = (const float*)d_in[11];
    const float* eWge = (const float*)d_in[12];
    const float* eWgn = (const float*)d_in[13];
    const float* ebg  = (const float*)d_in[14];
    const float* hWee = (const float*)d_in[15];
    const float* hWes = (const float*)d_in[16];
    const float* hWeg = (const float*)d_in[17];
    const float* hbe  = (const float*)d_in[18];
    const float* hWnn = (const float*)d_in[19];
    const float* hWni = (const float*)d_in[20];
    const float* hWng = (const float*)d_in[21];
    const float* hbn  = (const float*)d_in[22];
    const float* hWge = (const float*)d_in[23];
    const float* hWgn = (const float*)d_in[24];
    const float* hWgg = (const float*)d_in[25];
    const float* hbg  = (const float*)d_in[26];
    const float* roWn = (const float*)d_in[27];
    const float* robn = (const float*)d_in[28];
    const float* roWg = (const float*)d_in[29];
    const float* robg = (const float*)d_in[30];

    float*  ws    = (float*)d_ws;
    u32*    edat  = (u32*)(ws + OFF_EDAT);
    __half* sproj = (__half*)(ws + OFF_SPROJ);
    __half* pnn   = (__half*)(ws + OFF_PNN);
    int*    deg   = (int*)(ws + OFF_DEG);
    float*  gs    = ws + OFF_GS;
    int*    cur   = (int*)(ws + OFF_CUR);
    float* esum1 = gs + GS_ESUM1;
    float* nsum1 = gs + GS_NSUM1;
    float* esum2 = gs + GS_ESUM2;
    float* nsum2 = gs + GS_NSUM2;
    float* g1    = gs + GS_G1;
    float* gpe   = gs + GS_GPE;
    float* gpn   = gs + GS_GPN;
    float* out   = (float*)d_out;

    // zero deg [NN] + esum1/nsum1/esum2/nsum2 [3072] (contiguous)
    hipMemsetAsync(deg, 0, (size_t)(NN + 3072) * sizeof(float), stream);

    k_hist<<<NG * 4, 512, 0, stream>>>(rcv, deg);
    k_scan<<<NG, 320, 0, stream>>>(deg, cur);
    k_scatter<<<NE / 256, 256, 0, stream>>>(ef, snd, rcv, cur, edat);
    k_node_pre<<<NN / 256, 256, 0, stream>>>(nf, eWes, eWnn, sproj, pnn);
    k_enc<<<NN / 256, 256, 0, stream>>>(deg, cur, edat, sproj, pnn,
                                        eWee, ebe, eWni, ebn, hWes, hWnn, esum1, nsum1);
    k_glob_enc<<<1, 64, 0, stream>>>(esum1, nsum1, eWge, eWgn, ebg, hWeg, hWng, g1, gpe, gpn);
    k_hid<<<NN / 256, 256, 0, stream>>>(deg, cur, edat, sproj, pnn,
                                        eWee, ebe, hWee, hbe, gpe, hWni, hbn, gpn,
                                        roWn, robn, esum2, nsum2, out);
    k_glob_hid<<<1, 64, 0, stream>>>(esum2, nsum2, g1, hWge, hWgn, hWgg, hbg, roWg, robg, out + NN);
}

// Round 7
// 145.673 us; speedup vs baseline: 5.8283x; 1.2993x over previous
//
#include <hip/hip_runtime.h>
#include <hip/hip_bf16.h>
#include <hip/hip_fp16.h>

#define NN   102400
#define NG   64
#define NPG  1600
#define NE   1638400
#define EPG  25600
#define EPC  (EPG / 4)   // 6400 edges per chunk

typedef unsigned int u32;
typedef unsigned short u16;

// ---- workspace layout (float offsets), total NE + 22*NN + 4864 ≈ 15.6 MB ----
#define OFF_EDAT  0                       // u32[NE]: (sender_local<<16) | bf16(ef)
#define OFF_SPROJ (NE)                    // __half[NN*16]: [0..8)=enc p_es+ebe, [8..16)=pes2
#define OFF_PNN   (NE + 8 * NN)           // __half[NN*16]: p_nn+ebn -> n1@hWnn^T
#define OFF_DEG   (NE + 16 * NN)          // int[NN]
#define OFF_START (NE + 17 * NN)          // int[NN]: gather segment start
#define OFF_H4C   (NE + 18 * NN)          // int[4*NN]: chunk hists -> chunk cursor bases (in place)
#define OFF_GS    (NE + 22 * NN)          // sums etc (4864 floats)
// gs offsets
#define GS_ESUM1 0     // G*8
#define GS_NSUM1 512   // G*16
#define GS_ESUM2 1536  // G*8
#define GS_NSUM2 2048  // G*16
#define GS_G1    3072  // G*4
#define GS_GPE   3328  // G*8
#define GS_GPN   3840  // G*16

struct H8 { __half2 a, b, c, d; };

__device__ __forceinline__ void unpack8(const H8 v, float* o) {
    float2 t0 = __half22float2(v.a), t1 = __half22float2(v.b);
    float2 t2 = __half22float2(v.c), t3 = __half22float2(v.d);
    o[0]=t0.x; o[1]=t0.y; o[2]=t1.x; o[3]=t1.y; o[4]=t2.x; o[5]=t2.y; o[6]=t3.x; o[7]=t3.y;
}
__device__ __forceinline__ H8 pack8(const float* v) {
    H8 r;
    r.a = __floats2half2_rn(v[0], v[1]); r.b = __floats2half2_rn(v[2], v[3]);
    r.c = __floats2half2_rn(v[4], v[5]); r.d = __floats2half2_rn(v[6], v[7]);
    return r;
}
__device__ __forceinline__ u16 f2bf(float f) {
    u32 u = __float_as_uint(f);
    return (u16)((u + 0x7fffu + ((u >> 16) & 1u)) >> 16);
}
__device__ __forceinline__ float wsum(float v) {
#pragma unroll
    for (int o = 32; o >= 1; o >>= 1) v += __shfl_xor(v, o);
    return v;
}
__device__ __forceinline__ float sigmoidf_(float x) { return 1.f / (1.f + expf(-x)); }

// H1: per-chunk receiver histogram (LDS atomics only), plain stores to h4.
__global__ __launch_bounds__(512) void k_hist4(const int* __restrict__ rcv, int* __restrict__ h4) {
    __shared__ int h[NPG];
    const int g = blockIdx.x >> 2, c = blockIdx.x & 3;
    for (int i = threadIdx.x; i < NPG; i += 512) h[i] = 0;
    __syncthreads();
    const int base = g * EPG + c * EPC;
    for (int t = threadIdx.x; t < EPC; t += 512) atomicAdd(&h[rcv[base + t] - g * NPG], 1);
    __syncthreads();
    int* out = h4 + (size_t)(g * 4 + c) * NPG;
    for (int i = threadIdx.x; i < NPG; i += 512) out[i] = h[i];
}

// H2: per-graph scan: deg, start, and in-place chunk cursor bases in h4c.
__global__ __launch_bounds__(320) void k_scan(
    int* __restrict__ h4c, int* __restrict__ deg, int* __restrict__ start)
{
    __shared__ int part[320];
    const int g = blockIdx.x, tid = threadIdx.x;
    const int vb = tid * 5;
    int hc[5][4], d[5], pre[5];
    int ts = 0;
#pragma unroll
    for (int i = 0; i < 5; ++i) {
        const int v = vb + i;
#pragma unroll
        for (int c = 0; c < 4; ++c) hc[i][c] = h4c[(size_t)(g * 4 + c) * NPG + v];
        d[i] = hc[i][0] + hc[i][1] + hc[i][2] + hc[i][3];
        pre[i] = ts;
        ts += d[i];
    }
    part[tid] = ts;
    __syncthreads();
    for (int o = 1; o < 320; o <<= 1) {
        const int v = (tid >= o) ? part[tid - o] : 0;
        __syncthreads();
        part[tid] += v;
        __syncthreads();
    }
    const int off = g * EPG + part[tid] - ts;
#pragma unroll
    for (int i = 0; i < 5; ++i) {
        const int v = vb + i;
        const int st = off + pre[i];
        deg[g * NPG + v] = d[i];
        start[g * NPG + v] = st;
        int run = st;
#pragma unroll
        for (int c = 0; c < 4; ++c) {
            h4c[(size_t)(g * 4 + c) * NPG + v] = run;
            run += hc[i][c];
        }
    }
}

// H3: scatter edges into receiver-sorted order via LDS cursors (no global atomics).
__global__ __launch_bounds__(512) void k_scatter4(
    const float* __restrict__ ef, const int* __restrict__ snd, const int* __restrict__ rcv,
    const int* __restrict__ h4c, u32* __restrict__ edat)
{
    __shared__ int cur[NPG];
    const int g = blockIdx.x >> 2, c = blockIdx.x & 3;
    const int* cb = h4c + (size_t)(g * 4 + c) * NPG;
    for (int i = threadIdx.x; i < NPG; i += 512) cur[i] = cb[i];
    __syncthreads();
    const int base = g * EPG + c * EPC;
    for (int t = threadIdx.x; t < EPC; t += 512) {
        const int e = base + t;
        const int r = rcv[e] - g * NPG;
        const int p = atomicAdd(&cur[r], 1);
        const u32 s = (u32)(snd[e] - g * NPG);
        edat[p] = (s << 16) | (u32)f2bf(ef[e]);
    }
}

// K1: per-node encoder pre-projections (f32 in, f16 out); ebe folded into sproj, ebn into pnn.
__global__ __launch_bounds__(256) void k_node_pre(
    const float* __restrict__ nf,
    const float* __restrict__ Wes,   // [8][60]
    const float* __restrict__ Wnn,   // [16][60]
    const float* __restrict__ ebe, const float* __restrict__ ebn,
    __half* __restrict__ sproj, __half* __restrict__ pnn)
{
    __shared__ float wE[480], wN[960];
    for (int i = threadIdx.x; i < 480; i += 256) wE[i] = Wes[i];
    for (int i = threadIdx.x; i < 960; i += 256) wN[i] = Wnn[i];
    __syncthreads();
    const int v = blockIdx.x * 256 + threadIdx.x;
    const float4* row = reinterpret_cast<const float4*>(nf + (size_t)v * 60);
    float x[60];
#pragma unroll
    for (int i = 0; i < 15; ++i) {
        const float4 a = row[i];
        x[4 * i] = a.x; x[4 * i + 1] = a.y; x[4 * i + 2] = a.z; x[4 * i + 3] = a.w;
    }
    float pes[8], pn[16];
#pragma unroll
    for (int j = 0; j < 8; ++j) pes[j] = ebe[j];
#pragma unroll
    for (int j = 0; j < 16; ++j) pn[j] = ebn[j];
#pragma unroll
    for (int k = 0; k < 60; ++k) {
        const float xv = x[k];
#pragma unroll
        for (int j = 0; j < 8; ++j)  pes[j] = fmaf(xv, wE[j * 60 + k], pes[j]);
#pragma unroll
        for (int j = 0; j < 16; ++j) pn[j]  = fmaf(xv, wN[j * 60 + k], pn[j]);
    }
    H8* sp = reinterpret_cast<H8*>(sproj) + (size_t)v * 2;
    sp[0] = pack8(pes);
    H8* pp = reinterpret_cast<H8*>(pnn) + (size_t)v * 2;
    pp[0] = pack8(pn); pp[1] = pack8(pn + 8);
}

// K2: encoder edge (gather) + node layer + hidden pre-projections + graph sums.
__global__ __launch_bounds__(256) void k_enc(
    const int* __restrict__ deg, const int* __restrict__ start, const u32* __restrict__ edat,
    __half* __restrict__ sproj, __half* __restrict__ pnn,
    const float* __restrict__ eWee,
    const float* __restrict__ eWni,
    const float* __restrict__ hWes, const float* __restrict__ hWnn,
    float* __restrict__ esum, float* __restrict__ nsum)
{
    __shared__ float wNI[128], wES[128], wNN2[256];
    for (int i = threadIdx.x; i < 128; i += 256) { wNI[i] = eWni[i]; wES[i] = hWes[i]; }
    for (int i = threadIdx.x; i < 256; i += 256) wNN2[i] = hWnn[i];
    __syncthreads();
    const int v = blockIdx.x * 256 + threadIdx.x;
    const int g = v / NPG;
    float wee[8];
#pragma unroll
    for (int j = 0; j < 8; ++j) wee[j] = eWee[j];
    const int dg = deg[v];
    const int st = start[v];
    float m[8];
#pragma unroll
    for (int j = 0; j < 8; ++j) m[j] = 0.f;
    const H8* hb = reinterpret_cast<const H8*>(sproj) + (size_t)g * NPG * 2;
    for (int i = 0; i < dg; ++i) {
        const u32 w = edat[st + i];
        const float f = __uint_as_float((w & 0xffffu) << 16);
        const int s = (int)(w >> 16);
        float pv[8]; unpack8(hb[(size_t)s * 2], pv);
#pragma unroll
        for (int j = 0; j < 8; ++j) m[j] += fmaxf(0.f, fmaf(f, wee[j], pv[j]));
    }
#pragma unroll
    for (int j = 0; j < 8; ++j) {
        const float t = wsum(m[j]);
        if ((threadIdx.x & 63) == 0) atomicAdd(&esum[g * 8 + j], t);
    }
    const float ic = 1.f / fmaxf((float)dg, 1.f);
    float mk[8];
#pragma unroll
    for (int k = 0; k < 8; ++k) mk[k] = m[k] * ic;
    const H8* pp = reinterpret_cast<const H8*>(pnn) + (size_t)v * 2;
    float pn[16]; unpack8(pp[0], pn); unpack8(pp[1], pn + 8);
    float n1[16];
#pragma unroll
    for (int j = 0; j < 16; ++j) {
        float x = pn[j];
#pragma unroll
        for (int k = 0; k < 8; ++k) x = fmaf(mk[k], wNI[j * 8 + k], x);
        n1[j] = fmaxf(0.f, x);
    }
    float pe[8];
#pragma unroll
    for (int o = 0; o < 8; ++o) {
        float x = 0.f;
#pragma unroll
        for (int j = 0; j < 16; ++j) x = fmaf(n1[j], wES[o * 16 + j], x);
        pe[o] = x;
    }
    H8* spw = reinterpret_cast<H8*>(sproj) + (size_t)v * 2;
    spw[1] = pack8(pe);
    float pw[16];
#pragma unroll
    for (int o = 0; o < 16; ++o) {
        float x = 0.f;
#pragma unroll
        for (int j = 0; j < 16; ++j) x = fmaf(n1[j], wNN2[o * 16 + j], x);
        pw[o] = x;
    }
    H8* ppw = reinterpret_cast<H8*>(pnn) + (size_t)v * 2;
    ppw[0] = pack8(pw); ppw[1] = pack8(pw + 8);
#pragma unroll
    for (int j = 0; j < 16; ++j) {
        const float t = wsum(n1[j]);
        if ((threadIdx.x & 63) == 0) atomicAdd(&nsum[g * 16 + j], t);
    }
}

// K3: encoder global layer + g1 projections for hidden layers.
__global__ void k_glob_enc(
    const float* __restrict__ esum1, const float* __restrict__ nsum1,
    const float* __restrict__ Wge, const float* __restrict__ Wgn, const float* __restrict__ bg,
    const float* __restrict__ hWeg, const float* __restrict__ hWng,
    float* __restrict__ g1, float* __restrict__ gpe, float* __restrict__ gpn)
{
    const int g = threadIdx.x;
    if (g >= NG) return;
    float gv[4];
#pragma unroll
    for (int o = 0; o < 4; ++o) {
        float x = bg[o];
#pragma unroll
        for (int k = 0; k < 8; ++k)  x = fmaf(esum1[g * 8 + k] * (1.f / EPG), Wge[o * 8 + k], x);
#pragma unroll
        for (int k = 0; k < 16; ++k) x = fmaf(nsum1[g * 16 + k] * (1.f / NPG), Wgn[o * 16 + k], x);
        gv[o] = fmaxf(0.f, x);
        g1[g * 4 + o] = gv[o];
    }
#pragma unroll
    for (int j = 0; j < 8; ++j) {
        float x = 0.f;
#pragma unroll
        for (int o = 0; o < 4; ++o) x = fmaf(gv[o], hWeg[j * 4 + o], x);
        gpe[g * 8 + j] = x;
    }
#pragma unroll
    for (int j = 0; j < 16; ++j) {
        float x = 0.f;
#pragma unroll
        for (int o = 0; o < 4; ++o) x = fmaf(gv[o], hWng[j * 4 + o], x);
        gpn[g * 16 + j] = x;
    }
}

// K4: hidden edge (recompute e1, gather) + node layer + readout + graph sums.
__global__ __launch_bounds__(256) void k_hid(
    const int* __restrict__ deg, const int* __restrict__ start, const u32* __restrict__ edat,
    const __half* __restrict__ sproj, const __half* __restrict__ pnn,
    const float* __restrict__ eWee,
    const float* __restrict__ hWee, const float* __restrict__ hbe, const float* __restrict__ gpe,
    const float* __restrict__ hWni, const float* __restrict__ hbn, const float* __restrict__ gpn,
    const float* __restrict__ roWn, const float* __restrict__ robn,
    float* __restrict__ esum, float* __restrict__ nsum, float* __restrict__ outn)
{
    __shared__ float w2[64], wNI[128], rW[16];
    for (int i = threadIdx.x; i < 128; i += 256) wNI[i] = hWni[i];
    if (threadIdx.x < 64) w2[threadIdx.x] = hWee[threadIdx.x];
    if (threadIdx.x < 16) rW[threadIdx.x] = roWn[threadIdx.x];
    __syncthreads();
    const int v = blockIdx.x * 256 + threadIdx.x;
    const int g = v / NPG;
    float wee[8], add2[8];
#pragma unroll
    for (int j = 0; j < 8; ++j) { wee[j] = eWee[j]; add2[j] = gpe[g * 8 + j] + hbe[j]; }
    const int dg = deg[v];
    const int st = start[v];
    float m2[8];
#pragma unroll
    for (int j = 0; j < 8; ++j) m2[j] = 0.f;
    const H8* hb = reinterpret_cast<const H8*>(sproj) + (size_t)g * NPG * 2;
    for (int i = 0; i < dg; ++i) {
        const u32 w = edat[st + i];
        const float f = __uint_as_float((w & 0xffffu) << 16);
        const int s = (int)(w >> 16);
        float pv[8], qv[8];
        unpack8(hb[(size_t)s * 2], pv);
        unpack8(hb[(size_t)s * 2 + 1], qv);
        float e1[8];
#pragma unroll
        for (int j = 0; j < 8; ++j) e1[j] = fmaxf(0.f, fmaf(f, wee[j], pv[j]));
#pragma unroll
        for (int j = 0; j < 8; ++j) {
            float x = qv[j] + add2[j];
#pragma unroll
            for (int k = 0; k < 8; ++k) x = fmaf(e1[k], w2[j * 8 + k], x);
            m2[j] += fmaxf(0.f, x);
        }
    }
#pragma unroll
    for (int j = 0; j < 8; ++j) {
        const float t = wsum(m2[j]);
        if ((threadIdx.x & 63) == 0) atomicAdd(&esum[g * 8 + j], t);
    }
    const float ic = 1.f / fmaxf((float)dg, 1.f);
    float mk[8];
#pragma unroll
    for (int k = 0; k < 8; ++k) mk[k] = m2[k] * ic;
    const H8* pp = reinterpret_cast<const H8*>(pnn) + (size_t)v * 2;
    float pn[16]; unpack8(pp[0], pn); unpack8(pp[1], pn + 8);
    float z = robn[0];
    float n2[16];
#pragma unroll
    for (int j = 0; j < 16; ++j) {
        float x = pn[j] + gpn[g * 16 + j] + hbn[j];
#pragma unroll
        for (int k = 0; k < 8; ++k) x = fmaf(mk[k], wNI[j * 8 + k], x);
        n2[j] = fmaxf(0.f, x);
        z = fmaf(n2[j], rW[j], z);
    }
    outn[v] = sigmoidf_(z);
#pragma unroll
    for (int j = 0; j < 16; ++j) {
        const float t = wsum(n2[j]);
        if ((threadIdx.x & 63) == 0) atomicAdd(&nsum[g * 16 + j], t);
    }
}

// K5: hidden global layer + global readout.
__global__ void k_glob_hid(
    const float* __restrict__ esum2, const float* __restrict__ nsum2, const float* __restrict__ g1,
    const float* __restrict__ hWge, const float* __restrict__ hWgn,
    const float* __restrict__ hWgg, const float* __restrict__ hbg,
    const float* __restrict__ roWg, const float* __restrict__ robg,
    float* __restrict__ outg)
{
    const int g = threadIdx.x;
    if (g >= NG) return;
    float gv[4];
#pragma unroll
    for (int o = 0; o < 4; ++o) {
        float x = hbg[o];
#pragma unroll
        for (int k = 0; k < 8; ++k)  x = fmaf(esum2[g * 8 + k] * (1.f / EPG), hWge[o * 8 + k], x);
#pragma unroll
        for (int k = 0; k < 16; ++k) x = fmaf(nsum2[g * 16 + k] * (1.f / NPG), hWgn[o * 16 + k], x);
#pragma unroll
        for (int k = 0; k < 4; ++k)  x = fmaf(g1[g * 4 + k], hWgg[o * 4 + k], x);
        gv[o] = fmaxf(0.f, x);
    }
    float z = robg[0];
#pragma unroll
    for (int o = 0; o < 4; ++o) z = fmaf(gv[o], roWg[o], z);
    outg[g] = sigmoidf_(z);
}

extern "C" void kernel_launch(void* const* d_in, const int* in_sizes, int n_in,
                              void* d_out, int out_size, void* d_ws, size_t ws_size,
                              hipStream_t stream)
{
    const float* nf   = (const float*)d_in[0];
    const float* ef   = (const float*)d_in[1];
    const int*   snd  = (const int*)d_in[2];
    const int*   rcv  = (const int*)d_in[3];
    const float* eWee = (const float*)d_in[6];
    const float* eWes = (const float*)d_in[7];
    const float* ebe  = (const float*)d_in[8];
    const float* eWnn = (const float*)d_in[9];
    const float* eWni = (const float*)d_in[10];
    const float* ebn  = (const float*)d_in[11];
    const float* eWge = (const float*)d_in[12];
    const float* eWgn = (const float*)d_in[13];
    const float* ebg  = (const float*)d_in[14];
    const float* hWee = (const float*)d_in[15];
    const float* hWes = (const float*)d_in[16];
    const float* hWeg = (const float*)d_in[17];
    const float* hbe  = (const float*)d_in[18];
    const float* hWnn = (const float*)d_in[19];
    const float* hWni = (const float*)d_in[20];
    const float* hWng = (const float*)d_in[21];
    const float* hbn  = (const float*)d_in[22];
    const float* hWge = (const float*)d_in[23];
    const float* hWgn = (const float*)d_in[24];
    const float* hWgg = (const float*)d_in[25];
    const float* hbg  = (const float*)d_in[26];
    const float* roWn = (const float*)d_in[27];
    const float* robn = (const float*)d_in[28];
    const float* roWg = (const float*)d_in[29];
    const float* robg = (const float*)d_in[30];

    float*  ws    = (float*)d_ws;
    u32*    edat  = (u32*)(ws + OFF_EDAT);
    __half* sproj = (__half*)(ws + OFF_SPROJ);
    __half* pnn   = (__half*)(ws + OFF_PNN);
    int*    deg   = (int*)(ws + OFF_DEG);
    int*    start = (int*)(ws + OFF_START);
    int*    h4c   = (int*)(ws + OFF_H4C);
    float*  gs    = ws + OFF_GS;
    float* esum1 = gs + GS_ESUM1;
    float* nsum1 = gs + GS_NSUM1;
    float* esum2 = gs + GS_ESUM2;
    float* nsum2 = gs + GS_NSUM2;
    float* g1    = gs + GS_G1;
    float* gpe   = gs + GS_GPE;
    float* gpn   = gs + GS_GPN;
    float* out   = (float*)d_out;

    // zero graph-sum accumulators only
    hipMemsetAsync(gs, 0, 3072 * sizeof(float), stream);

    k_hist4<<<NG * 4, 512, 0, stream>>>(rcv, h4c);
    k_scan<<<NG, 320, 0, stream>>>(h4c, deg, start);
    k_scatter4<<<NG * 4, 512, 0, stream>>>(ef, snd, rcv, h4c, edat);
    k_node_pre<<<NN / 256, 256, 0, stream>>>(nf, eWes, eWnn, ebe, ebn, sproj, pnn);
    k_enc<<<NN / 256, 256, 0, stream>>>(deg, start, edat, sproj, pnn,
                                        eWee, eWni, hWes, hWnn, esum1, nsum1);
    k_glob_enc<<<1, 64, 0, stream>>>(esum1, nsum1, eWge, eWgn, ebg, hWeg, hWng, g1, gpe, gpn);
    k_hid<<<NN / 256, 256, 0, stream>>>(deg, start, edat, sproj, pnn,
                                        eWee, hWee, hbe, gpe, hWni, hbn, gpn,
                                        roWn, robn, esum2, nsum2, out);
    k_glob_hid<<<1, 64, 0, stream>>>(esum2, nsum2, g1, hWge, hWgn, hWgg, hbg, roWg, robg, out + NN);
}

// Round 8
// 144.028 us; speedup vs baseline: 5.8949x; 1.0114x over previous
//
#include <hip/hip_runtime.h>
#include <hip/hip_bf16.h>
#include <hip/hip_fp16.h>

#define NN   102400
#define NG   64
#define NPG  1600
#define NE   1638400
#define EPG  25600
#define EPC  (EPG / 4)   // 6400 edges per chunk

typedef unsigned int u32;
typedef unsigned short u16;

// ---- workspace layout (float offsets), total NE + 22*NN + 4864 ≈ 15.6 MB ----
#define OFF_EDAT  0                       // u32[NE]: (sender_local<<16) | bf16(ef)
#define OFF_SPROJ (NE)                    // __half[NN*16]: [0..8)=enc p_es+ebe, [8..16)=pes2
#define OFF_PNN   (NE + 8 * NN)           // __half[NN*16]: p_nn+ebn -> n1@hWnn^T
#define OFF_DEG   (NE + 16 * NN)          // int[NN]
#define OFF_START (NE + 17 * NN)          // int[NN]: gather segment start
#define OFF_H4C   (NE + 18 * NN)          // int[4*NN]: chunk hists -> chunk cursor bases (in place)
#define OFF_GS    (NE + 22 * NN)          // sums etc (4864 floats)
// gs offsets
#define GS_ESUM1 0     // G*8
#define GS_NSUM1 512   // G*16
#define GS_ESUM2 1536  // G*8
#define GS_NSUM2 2048  // G*16
#define GS_G1    3072  // G*4
#define GS_GPE   3328  // G*8
#define GS_GPN   3840  // G*16

struct H8 { __half2 a, b, c, d; };
struct H4 { __half2 a, b; };

__device__ __forceinline__ void unpack8(const H8 v, float* o) {
    float2 t0 = __half22float2(v.a), t1 = __half22float2(v.b);
    float2 t2 = __half22float2(v.c), t3 = __half22float2(v.d);
    o[0]=t0.x; o[1]=t0.y; o[2]=t1.x; o[3]=t1.y; o[4]=t2.x; o[5]=t2.y; o[6]=t3.x; o[7]=t3.y;
}
__device__ __forceinline__ H8 pack8(const float* v) {
    H8 r;
    r.a = __floats2half2_rn(v[0], v[1]); r.b = __floats2half2_rn(v[2], v[3]);
    r.c = __floats2half2_rn(v[4], v[5]); r.d = __floats2half2_rn(v[6], v[7]);
    return r;
}
__device__ __forceinline__ H4 pack4(const float* v) {
    H4 r;
    r.a = __floats2half2_rn(v[0], v[1]); r.b = __floats2half2_rn(v[2], v[3]);
    return r;
}
__device__ __forceinline__ u16 f2bf(float f) {
    u32 u = __float_as_uint(f);
    return (u16)((u + 0x7fffu + ((u >> 16) & 1u)) >> 16);
}
// sum over the 32 lanes of the same parity class (strides 2..32 preserve parity)
__device__ __forceinline__ float wsum_par(float v) {
#pragma unroll
    for (int o = 2; o <= 32; o <<= 1) v += __shfl_xor(v, o);
    return v;
}
__device__ __forceinline__ float sigmoidf_(float x) { return 1.f / (1.f + expf(-x)); }

// H1: per-chunk receiver histogram (LDS atomics only), plain stores to h4.
__global__ __launch_bounds__(512) void k_hist4(const int* __restrict__ rcv, int* __restrict__ h4) {
    __shared__ int h[NPG];
    const int g = blockIdx.x >> 2, c = blockIdx.x & 3;
    for (int i = threadIdx.x; i < NPG; i += 512) h[i] = 0;
    __syncthreads();
    const int base = g * EPG + c * EPC;
    for (int t = threadIdx.x; t < EPC; t += 512) atomicAdd(&h[rcv[base + t] - g * NPG], 1);
    __syncthreads();
    int* out = h4 + (size_t)(g * 4 + c) * NPG;
    for (int i = threadIdx.x; i < NPG; i += 512) out[i] = h[i];
}

// H2: per-graph scan: deg, start, and in-place chunk cursor bases in h4c.
__global__ __launch_bounds__(320) void k_scan(
    int* __restrict__ h4c, int* __restrict__ deg, int* __restrict__ start)
{
    __shared__ int part[320];
    const int g = blockIdx.x, tid = threadIdx.x;
    const int vb = tid * 5;
    int hc[5][4], d[5], pre[5];
    int ts = 0;
#pragma unroll
    for (int i = 0; i < 5; ++i) {
        const int v = vb + i;
#pragma unroll
        for (int c = 0; c < 4; ++c) hc[i][c] = h4c[(size_t)(g * 4 + c) * NPG + v];
        d[i] = hc[i][0] + hc[i][1] + hc[i][2] + hc[i][3];
        pre[i] = ts;
        ts += d[i];
    }
    part[tid] = ts;
    __syncthreads();
    for (int o = 1; o < 320; o <<= 1) {
        const int v = (tid >= o) ? part[tid - o] : 0;
        __syncthreads();
        part[tid] += v;
        __syncthreads();
    }
    const int off = g * EPG + part[tid] - ts;
#pragma unroll
    for (int i = 0; i < 5; ++i) {
        const int v = vb + i;
        const int st = off + pre[i];
        deg[g * NPG + v] = d[i];
        start[g * NPG + v] = st;
        int run = st;
#pragma unroll
        for (int c = 0; c < 4; ++c) {
            h4c[(size_t)(g * 4 + c) * NPG + v] = run;
            run += hc[i][c];
        }
    }
}

// H3: scatter edges into receiver-sorted order via LDS cursors (no global atomics).
__global__ __launch_bounds__(512) void k_scatter4(
    const float* __restrict__ ef, const int* __restrict__ snd, const int* __restrict__ rcv,
    const int* __restrict__ h4c, u32* __restrict__ edat)
{
    __shared__ int cur[NPG];
    const int g = blockIdx.x >> 2, c = blockIdx.x & 3;
    const int* cb = h4c + (size_t)(g * 4 + c) * NPG;
    for (int i = threadIdx.x; i < NPG; i += 512) cur[i] = cb[i];
    __syncthreads();
    const int base = g * EPG + c * EPC;
    for (int t = threadIdx.x; t < EPC; t += 512) {
        const int e = base + t;
        const int r = rcv[e] - g * NPG;
        const int p = atomicAdd(&cur[r], 1);
        const u32 s = (u32)(snd[e] - g * NPG);
        edat[p] = (s << 16) | (u32)f2bf(ef[e]);
    }
}

// K1: per-node encoder pre-projections (f32 in, f16 out); biases folded; also zeros gs.
__global__ __launch_bounds__(256) void k_node_pre(
    const float* __restrict__ nf,
    const float* __restrict__ Wes,   // [8][60]
    const float* __restrict__ Wnn,   // [16][60]
    const float* __restrict__ ebe, const float* __restrict__ ebn,
    __half* __restrict__ sproj, __half* __restrict__ pnn, float* __restrict__ gs)
{
    __shared__ float wE[480], wN[960];
    for (int i = threadIdx.x; i < 480; i += 256) wE[i] = Wes[i];
    for (int i = threadIdx.x; i < 960; i += 256) wN[i] = Wnn[i];
    if (blockIdx.x == 0) {
        for (int i = threadIdx.x; i < 3072; i += 256) gs[i] = 0.f;
    }
    __syncthreads();
    const int v = blockIdx.x * 256 + threadIdx.x;
    const float4* row = reinterpret_cast<const float4*>(nf + (size_t)v * 60);
    float x[60];
#pragma unroll
    for (int i = 0; i < 15; ++i) {
        const float4 a = row[i];
        x[4 * i] = a.x; x[4 * i + 1] = a.y; x[4 * i + 2] = a.z; x[4 * i + 3] = a.w;
    }
    float pes[8], pn[16];
#pragma unroll
    for (int j = 0; j < 8; ++j) pes[j] = ebe[j];
#pragma unroll
    for (int j = 0; j < 16; ++j) pn[j] = ebn[j];
#pragma unroll
    for (int k = 0; k < 60; ++k) {
        const float xv = x[k];
#pragma unroll
        for (int j = 0; j < 8; ++j)  pes[j] = fmaf(xv, wE[j * 60 + k], pes[j]);
#pragma unroll
        for (int j = 0; j < 16; ++j) pn[j]  = fmaf(xv, wN[j * 60 + k], pn[j]);
    }
    H8* sp = reinterpret_cast<H8*>(sproj) + (size_t)v * 2;
    sp[0] = pack8(pes);
    H8* pp = reinterpret_cast<H8*>(pnn) + (size_t)v * 2;
    pp[0] = pack8(pn); pp[1] = pack8(pn + 8);
}

// K2: encoder edge gather + node layer, 2 threads/node, ILP-4 batched gathers.
__global__ __launch_bounds__(256) void k_enc(
    const int* __restrict__ deg, const int* __restrict__ start, const u32* __restrict__ edat,
    __half* __restrict__ sproj, __half* __restrict__ pnn,
    const float* __restrict__ eWee,
    const float* __restrict__ eWni,
    const float* __restrict__ hWes, const float* __restrict__ hWnn,
    float* __restrict__ esum, float* __restrict__ nsum)
{
    __shared__ float wNI[128], wES[128], wNN2[256];
    for (int i = threadIdx.x; i < 128; i += 256) { wNI[i] = eWni[i]; wES[i] = hWes[i]; }
    wNN2[threadIdx.x] = hWnn[threadIdx.x];
    __syncthreads();
    const int t = blockIdx.x * 256 + threadIdx.x;
    const int v = t >> 1, h = t & 1;
    const int g = v / NPG;
    float wee[8];
#pragma unroll
    for (int j = 0; j < 8; ++j) wee[j] = eWee[j];
    const int dg = deg[v];
    const int st = start[v];
    const int half0 = dg >> 1;
    int i = st + (h ? half0 : 0);
    const int iend = st + (h ? dg : half0);
    float m[8];
#pragma unroll
    for (int j = 0; j < 8; ++j) m[j] = 0.f;
    const H8* hb = reinterpret_cast<const H8*>(sproj) + (size_t)g * NPG * 2;

#define ENC_EDGE(W, A) { \
    const float f_ = __uint_as_float(((W) & 0xffffu) << 16); \
    float pv_[8]; unpack8((A), pv_); \
    _Pragma("unroll") \
    for (int j = 0; j < 8; ++j) m[j] += fmaxf(0.f, fmaf(f_, wee[j], pv_[j])); }

    for (; i + 4 <= iend; i += 4) {
        const u32 w0 = edat[i], w1 = edat[i + 1], w2v = edat[i + 2], w3v = edat[i + 3];
        const H8 A0 = hb[(size_t)(w0 >> 16) * 2];
        const H8 A1 = hb[(size_t)(w1 >> 16) * 2];
        const H8 A2 = hb[(size_t)(w2v >> 16) * 2];
        const H8 A3 = hb[(size_t)(w3v >> 16) * 2];
        ENC_EDGE(w0, A0) ENC_EDGE(w1, A1) ENC_EDGE(w2v, A2) ENC_EDGE(w3v, A3)
    }
    for (; i < iend; ++i) {
        const u32 w = edat[i];
        const H8 A = hb[(size_t)(w >> 16) * 2];
        ENC_EDGE(w, A)
    }
#undef ENC_EDGE

    // pair combine -> both lanes hold full segment sum
#pragma unroll
    for (int j = 0; j < 8; ++j) m[j] += __shfl_xor(m[j], 1);
#pragma unroll
    for (int j = 0; j < 8; ++j) {
        const float s = wsum_par(m[j]);
        if ((threadIdx.x & 63) == 0) atomicAdd(&esum[g * 8 + j], s);
    }
    const float ic = 1.f / fmaxf((float)dg, 1.f);
    float mk[8];
#pragma unroll
    for (int k = 0; k < 8; ++k) mk[k] = m[k] * ic;
    // node layer: own j-half
    const H8* pp = reinterpret_cast<const H8*>(pnn) + (size_t)v * 2;
    float pn8[8]; unpack8(pp[h], pn8);
    float n1[8];
#pragma unroll
    for (int jj = 0; jj < 8; ++jj) {
        float x = pn8[jj];
#pragma unroll
        for (int k = 0; k < 8; ++k) x = fmaf(mk[k], wNI[(h * 8 + jj) * 8 + k], x);
        n1[jj] = fmaxf(0.f, x);
    }
    // exchange halves -> full n1[16]
    float n1o[8];
#pragma unroll
    for (int jj = 0; jj < 8; ++jj) n1o[jj] = __shfl_xor(n1[jj], 1);
    float full[16];
#pragma unroll
    for (int jj = 0; jj < 8; ++jj) {
        full[jj]     = h ? n1o[jj] : n1[jj];
        full[8 + jj] = h ? n1[jj]  : n1o[jj];
    }
    // pe: 4 outputs per lane (o = h*4 .. h*4+3)
    float pe4[4];
#pragma unroll
    for (int oo = 0; oo < 4; ++oo) {
        const int o = h * 4 + oo;
        float x = 0.f;
#pragma unroll
        for (int j = 0; j < 16; ++j) x = fmaf(full[j], wES[o * 16 + j], x);
        pe4[oo] = x;
    }
    *reinterpret_cast<H4*>(sproj + (size_t)v * 16 + 8 + h * 4) = pack4(pe4);
    // pw: 8 outputs per lane (o = h*8 .. h*8+7)
    float pw8[8];
#pragma unroll
    for (int oo = 0; oo < 8; ++oo) {
        const int o = h * 8 + oo;
        float x = 0.f;
#pragma unroll
        for (int j = 0; j < 16; ++j) x = fmaf(full[j], wNN2[o * 16 + j], x);
        pw8[oo] = x;
    }
    reinterpret_cast<H8*>(pnn)[(size_t)v * 2 + h] = pack8(pw8);
    // nsum: own-half, parity-class reduce
#pragma unroll
    for (int jj = 0; jj < 8; ++jj) {
        const float s = wsum_par(n1[jj]);
        if ((threadIdx.x & 63) == h) atomicAdd(&nsum[g * 16 + h * 8 + jj], s);
    }
}

// K3: encoder global layer + g1 projections for hidden layers.
__global__ void k_glob_enc(
    const float* __restrict__ esum1, const float* __restrict__ nsum1,
    const float* __restrict__ Wge, const float* __restrict__ Wgn, const float* __restrict__ bg,
    const float* __restrict__ hWeg, const float* __restrict__ hWng,
    float* __restrict__ g1, float* __restrict__ gpe, float* __restrict__ gpn)
{
    const int g = threadIdx.x;
    if (g >= NG) return;
    float gv[4];
#pragma unroll
    for (int o = 0; o < 4; ++o) {
        float x = bg[o];
#pragma unroll
        for (int k = 0; k < 8; ++k)  x = fmaf(esum1[g * 8 + k] * (1.f / EPG), Wge[o * 8 + k], x);
#pragma unroll
        for (int k = 0; k < 16; ++k) x = fmaf(nsum1[g * 16 + k] * (1.f / NPG), Wgn[o * 16 + k], x);
        gv[o] = fmaxf(0.f, x);
        g1[g * 4 + o] = gv[o];
    }
#pragma unroll
    for (int j = 0; j < 8; ++j) {
        float x = 0.f;
#pragma unroll
        for (int o = 0; o < 4; ++o) x = fmaf(gv[o], hWeg[j * 4 + o], x);
        gpe[g * 8 + j] = x;
    }
#pragma unroll
    for (int j = 0; j < 16; ++j) {
        float x = 0.f;
#pragma unroll
        for (int o = 0; o < 4; ++o) x = fmaf(gv[o], hWng[j * 4 + o], x);
        gpn[g * 16 + j] = x;
    }
}

// K4: hidden edge gather (recompute e1) + node layer + readout, 2 threads/node, ILP-4.
__global__ __launch_bounds__(256) void k_hid(
    const int* __restrict__ deg, const int* __restrict__ start, const u32* __restrict__ edat,
    const __half* __restrict__ sproj, const __half* __restrict__ pnn,
    const float* __restrict__ eWee,
    const float* __restrict__ hWee, const float* __restrict__ hbe, const float* __restrict__ gpe,
    const float* __restrict__ hWni, const float* __restrict__ hbn, const float* __restrict__ gpn,
    const float* __restrict__ roWn, const float* __restrict__ robn,
    float* __restrict__ esum, float* __restrict__ nsum, float* __restrict__ outn)
{
    __shared__ float w2[64], wNI[128], rW[16];
    for (int i = threadIdx.x; i < 128; i += 256) wNI[i] = hWni[i];
    if (threadIdx.x < 64) w2[threadIdx.x] = hWee[threadIdx.x];
    if (threadIdx.x < 16) rW[threadIdx.x] = roWn[threadIdx.x];
    __syncthreads();
    const int t = blockIdx.x * 256 + threadIdx.x;
    const int v = t >> 1, h = t & 1;
    const int g = v / NPG;
    float wee[8], add2[8];
#pragma unroll
    for (int j = 0; j < 8; ++j) { wee[j] = eWee[j]; add2[j] = gpe[g * 8 + j] + hbe[j]; }
    const int dg = deg[v];
    const int st = start[v];
    const int half0 = dg >> 1;
    int i = st + (h ? half0 : 0);
    const int iend = st + (h ? dg : half0);
    float m2[8];
#pragma unroll
    for (int j = 0; j < 8; ++j) m2[j] = 0.f;
    const H8* hb = reinterpret_cast<const H8*>(sproj) + (size_t)g * NPG * 2;

#define HID_EDGE(W, A, B) { \
    const float f_ = __uint_as_float(((W) & 0xffffu) << 16); \
    float pv_[8], qv_[8]; unpack8((A), pv_); unpack8((B), qv_); \
    float e1_[8]; \
    _Pragma("unroll") \
    for (int j = 0; j < 8; ++j) e1_[j] = fmaxf(0.f, fmaf(f_, wee[j], pv_[j])); \
    _Pragma("unroll") \
    for (int j = 0; j < 8; ++j) { \
        float x_ = qv_[j] + add2[j]; \
        _Pragma("unroll") \
        for (int k = 0; k < 8; ++k) x_ = fmaf(e1_[k], w2[j * 8 + k], x_); \
        m2[j] += fmaxf(0.f, x_); } }

    for (; i + 4 <= iend; i += 4) {
        const u32 w0 = edat[i], w1 = edat[i + 1], w2v = edat[i + 2], w3v = edat[i + 3];
        const size_t s0 = (size_t)(w0 >> 16) * 2, s1 = (size_t)(w1 >> 16) * 2;
        const size_t s2 = (size_t)(w2v >> 16) * 2, s3 = (size_t)(w3v >> 16) * 2;
        const H8 A0 = hb[s0], B0 = hb[s0 + 1];
        const H8 A1 = hb[s1], B1 = hb[s1 + 1];
        const H8 A2 = hb[s2], B2 = hb[s2 + 1];
        const H8 A3 = hb[s3], B3 = hb[s3 + 1];
        HID_EDGE(w0, A0, B0) HID_EDGE(w1, A1, B1) HID_EDGE(w2v, A2, B2) HID_EDGE(w3v, A3, B3)
    }
    for (; i < iend; ++i) {
        const u32 w = edat[i];
        const size_t s = (size_t)(w >> 16) * 2;
        const H8 A = hb[s], B = hb[s + 1];
        HID_EDGE(w, A, B)
    }
#undef HID_EDGE

#pragma unroll
    for (int j = 0; j < 8; ++j) m2[j] += __shfl_xor(m2[j], 1);
#pragma unroll
    for (int j = 0; j < 8; ++j) {
        const float s = wsum_par(m2[j]);
        if ((threadIdx.x & 63) == 0) atomicAdd(&esum[g * 8 + j], s);
    }
    const float ic = 1.f / fmaxf((float)dg, 1.f);
    float mk[8];
#pragma unroll
    for (int k = 0; k < 8; ++k) mk[k] = m2[k] * ic;
    const H8* pp = reinterpret_cast<const H8*>(pnn) + (size_t)v * 2;
    float pn8[8]; unpack8(pp[h], pn8);
    float zp = 0.f;
    float n2[8];
#pragma unroll
    for (int jj = 0; jj < 8; ++jj) {
        const int j = h * 8 + jj;
        float x = pn8[jj] + gpn[g * 16 + j] + hbn[j];
#pragma unroll
        for (int k = 0; k < 8; ++k) x = fmaf(mk[k], wNI[j * 8 + k], x);
        n2[jj] = fmaxf(0.f, x);
        zp = fmaf(n2[jj], rW[j], zp);
    }
    const float z = zp + __shfl_xor(zp, 1);
    if (h == 0) outn[v] = sigmoidf_(z + robn[0]);
#pragma unroll
    for (int jj = 0; jj < 8; ++jj) {
        const float s = wsum_par(n2[jj]);
        if ((threadIdx.x & 63) == h) atomicAdd(&nsum[g * 16 + h * 8 + jj], s);
    }
}

// K5: hidden global layer + global readout.
__global__ void k_glob_hid(
    const float* __restrict__ esum2, const float* __restrict__ nsum2, const float* __restrict__ g1,
    const float* __restrict__ hWge, const float* __restrict__ hWgn,
    const float* __restrict__ hWgg, const float* __restrict__ hbg,
    const float* __restrict__ roWg, const float* __restrict__ robg,
    float* __restrict__ outg)
{
    const int g = threadIdx.x;
    if (g >= NG) return;
    float gv[4];
#pragma unroll
    for (int o = 0; o < 4; ++o) {
        float x = hbg[o];
#pragma unroll
        for (int k = 0; k < 8; ++k)  x = fmaf(esum2[g * 8 + k] * (1.f / EPG), hWge[o * 8 + k], x);
#pragma unroll
        for (int k = 0; k < 16; ++k) x = fmaf(nsum2[g * 16 + k] * (1.f / NPG), hWgn[o * 16 + k], x);
#pragma unroll
        for (int k = 0; k < 4; ++k)  x = fmaf(g1[g * 4 + k], hWgg[o * 4 + k], x);
        gv[o] = fmaxf(0.f, x);
    }
    float z = robg[0];
#pragma unroll
    for (int o = 0; o < 4; ++o) z = fmaf(gv[o], roWg[o], z);
    outg[g] = sigmoidf_(z);
}

extern "C" void kernel_launch(void* const* d_in, const int* in_sizes, int n_in,
                              void* d_out, int out_size, void* d_ws, size_t ws_size,
                              hipStream_t stream)
{
    const float* nf   = (const float*)d_in[0];
    const float* ef   = (const float*)d_in[1];
    const int*   snd  = (const int*)d_in[2];
    const int*   rcv  = (const int*)d_in[3];
    const float* eWee = (const float*)d_in[6];
    const float* eWes = (const float*)d_in[7];
    const float* ebe  = (const float*)d_in[8];
    const float* eWnn = (const float*)d_in[9];
    const float* eWni = (const float*)d_in[10];
    const float* ebn  = (const float*)d_in[11];
    const float* eWge = (const float*)d_in[12];
    const float* eWgn = (const float*)d_in[13];
    const float* ebg  = (const float*)d_in[14];
    const float* hWee = (const float*)d_in[15];
    const float* hWes = (const float*)d_in[16];
    const float* hWeg = (const float*)d_in[17];
    const float* hbe  = (const float*)d_in[18];
    const float* hWnn = (const float*)d_in[19];
    const float* hWni = (const float*)d_in[20];
    const float* hWng = (const float*)d_in[21];
    const float* hbn  = (const float*)d_in[22];
    const float* hWge = (const float*)d_in[23];
    const float* hWgn = (const float*)d_in[24];
    const float* hWgg = (const float*)d_in[25];
    const float* hbg  = (const float*)d_in[26];
    const float* roWn = (const float*)d_in[27];
    const float* robn = (const float*)d_in[28];
    const float* roWg = (const float*)d_in[29];
    const float* robg = (const float*)d_in[30];

    float*  ws    = (float*)d_ws;
    u32*    edat  = (u32*)(ws + OFF_EDAT);
    __half* sproj = (__half*)(ws + OFF_SPROJ);
    __half* pnn   = (__half*)(ws + OFF_PNN);
    int*    deg   = (int*)(ws + OFF_DEG);
    int*    start = (int*)(ws + OFF_START);
    int*    h4c   = (int*)(ws + OFF_H4C);
    float*  gs    = ws + OFF_GS;
    float* esum1 = gs + GS_ESUM1;
    float* nsum1 = gs + GS_NSUM1;
    float* esum2 = gs + GS_ESUM2;
    float* nsum2 = gs + GS_NSUM2;
    float* g1    = gs + GS_G1;
    float* gpe   = gs + GS_GPE;
    float* gpn   = gs + GS_GPN;
    float* out   = (float*)d_out;

    k_hist4<<<NG * 4, 512, 0, stream>>>(rcv, h4c);
    k_scan<<<NG, 320, 0, stream>>>(h4c, deg, start);
    k_scatter4<<<NG * 4, 512, 0, stream>>>(ef, snd, rcv, h4c, edat);
    k_node_pre<<<NN / 256, 256, 0, stream>>>(nf, eWes, eWnn, ebe, ebn, sproj, pnn, gs);
    k_enc<<<NN * 2 / 256, 256, 0, stream>>>(deg, start, edat, sproj, pnn,
                                            eWee, eWni, hWes, hWnn, esum1, nsum1);
    k_glob_enc<<<1, 64, 0, stream>>>(esum1, nsum1, eWge, eWgn, ebg, hWeg, hWng, g1, gpe, gpn);
    k_hid<<<NN * 2 / 256, 256, 0, stream>>>(deg, start, edat, sproj, pnn,
                                            eWee, hWee, hbe, gpe, hWni, hbn, gpn,
                                            roWn, robn, esum2, nsum2, out);
    k_glob_hid<<<1, 64, 0, stream>>>(esum2, nsum2, g1, hWge, hWgn, hWgg, hbg, roWg, robg, out + NN);
}